// Round 2
// baseline (267.885 us; speedup 1.0000x reference)
//
#include <hip/hip_runtime.h>
#include <math.h>

#define P_NUM   16320
#define B_NUM   32
#define NCLS    21
#define TOPK    500
#define CONF_THR 0.01f
#define NMS_THR  0.45f
#define OBJ_THR  0.01f
#define NBUCKET 2048
#define CAND_CAP 1024
#define NTHREADS 512
#define CHUNK   256
#define NTASK   (B_NUM * (NCLS - 1))
#define TRI_WORDS 2304       // sum_{b=0..7} 64*(8-b)
#define NEAR_EPS 1e-6f       // guard zone ~2^-25 rel; 1e-6 is safely wider

typedef unsigned long long u64;
typedef unsigned int u32;

struct SMemA {
    u32 hist[NBUCKET];    // 8192 B
    int csum[NTHREADS];   // 2048 B
    int gsum[64];         // 256 B
    u64 keys[CAND_CAP];   // 8192 B  (also cross-wave sort exchange buffer)
};

struct SMem {
    union {
        SMemA a;          // phases 0-4
        u64 tri[TRI_WORDS]; // 18432 B triangular mask (phases 6-7)
    } u;                  // 18688 B
    float4 sbox[512];     // 8192 B (padded to 512 with sentinels)
    float  sscore[512];   // 2048 B
    float  sarea[512];    // 2048 B
    int    order[512];    // 2048 B
    u64    rowflag[8];
    u64    alive[8];
    int    wordpref[8];
    int    cand_count;
    int    bstar;
    int    n_emit;
};                        // ~33.2 KB -> 4 blocks/CU (wave-capped)

// ---- mask + transpose odm_conf into per-task contiguous score arrays ----
__global__ __launch_bounds__(256)
void mask_transpose(const float* __restrict__ arm_conf,
                    const float* __restrict__ odm_conf,
                    float* __restrict__ ws) {
    __shared__ float tile[NCLS][CHUNK + 1];
    __shared__ float obj[CHUNK];
    const int blk = blockIdx.x;
    const int b = blk >> 6;
    const int ch = blk & 63;
    const int p0 = ch * CHUNK;
    const int np = min(CHUNK, P_NUM - p0);    // 256, last chunk 192
    const int tid = threadIdx.x;

    const float4* oc4 = (const float4*)(odm_conf + ((size_t)b * P_NUM + p0) * NCLS);
    const float* ac = arm_conf + ((size_t)b * P_NUM + p0) * 2;
    const int count4 = (np * NCLS) / 4;       // 1344 or 1008
    for (int q = tid; q < count4; q += 256) {
        float4 v = oc4[q];                    // coalesced 16B
        int f = 4 * q;
        {
            int p = f / NCLS;       int cc = f - p * NCLS;       tile[cc][p] = v.x;
        }
        {
            int p = (f+1) / NCLS;   int cc = (f+1) - p * NCLS;   tile[cc][p] = v.y;
        }
        {
            int p = (f+2) / NCLS;   int cc = (f+2) - p * NCLS;   tile[cc][p] = v.z;
        }
        {
            int p = (f+3) / NCLS;   int cc = (f+3) - p * NCLS;   tile[cc][p] = v.w;
        }
    }
    if (tid < np) obj[tid] = ac[tid * 2 + 1];
    __syncthreads();

    const int nv = np / 4;                    // 64 or 48
    const int total = 20 * nv;
    for (int i = tid; i < total; i += 256) {
        int cc = i / nv;                      // 0..19 -> class cc+1
        int pp = i - cc * nv;
        const float* t = &tile[cc + 1][4 * pp];
        float4 ov = make_float4(
            (obj[4*pp+0] > OBJ_THR) ? t[0] : 0.0f,
            (obj[4*pp+1] > OBJ_THR) ? t[1] : 0.0f,
            (obj[4*pp+2] > OBJ_THR) ? t[2] : 0.0f,
            (obj[4*pp+3] > OBJ_THR) ? t[3] : 0.0f);
        float4* w4 = (float4*)(ws + ((size_t)(b * 20 + cc)) * P_NUM + p0);
        w4[pp] = ov;                          // coalesced 16B store
    }
}

// wave-uniform broadcast of lane jj's value (v_readlane -> SGPR, pure VALU)
__device__ __forceinline__ float rl(float x, int l) {
    return __int_as_float(__builtin_amdgcn_readlane(__float_as_int(x), l));
}

// One 64-column IoU block for this lane's row. Branchless hot path; EXACT
// variant replicates the reference's fl(inter/denom) > 0.45f decision and is
// run only when a lane lands in the fma-vs-div disagreement guard zone.
template <bool EXACT>
__device__ __forceinline__ u64 iou_block(float4 bj, float ajv, float4 bi, float ai,
                                         int i, int j0, int& nearf) {
    u64 bits = 0ull;
    #pragma unroll 16
    for (int jj = 0; jj < 64; ++jj) {
        float sx1 = rl(bj.x, jj);
        float sy1 = rl(bj.y, jj);
        float sx2 = rl(bj.z, jj);
        float sy2 = rl(bj.w, jj);
        float aj  = rl(ajv, jj);
        float xx1 = fmaxf(sx1, bi.x);
        float yy1 = fmaxf(sy1, bi.y);
        float xx2 = fminf(sx2, bi.z);
        float yy2 = fminf(sy2, bi.w);
        float iw = fmaxf(__fsub_rn(xx2, xx1), 0.0f);
        float ih = fmaxf(__fsub_rn(yy2, yy1), 0.0f);
        float inter = __fmul_rn(iw, ih);
        float denom = __fadd_rn(__fsub_rn(aj, inter), ai);   // (aj - inter) + ai, ref order
        bool sup;
        if (EXACT) {
            sup = (__fdiv_rn(inter, denom) > NMS_THR);
        } else {
            // sign(fma) == sign(inter - 0.45*denom) exactly (single rounding).
            float d = __builtin_fmaf(-NMS_THR, denom, inter);
            sup = (d > 0.0f);
            nearf |= (int)((inter > 0.0f) && (fabsf(d) <= __fmul_rn(denom, NEAR_EPS)));
        }
        bool on = sup && ((j0 + jj) > i);
        // shift-insert: element jj ends at bit jj after 64 steps
        bits = (bits >> 1) | (on ? 0x8000000000000000ull : 0ull);
    }
    return bits;
}

template <bool PACKED>
__global__ __launch_bounds__(NTHREADS, 8)
void refinedet_main(const float* __restrict__ arm_loc,
                    const float* __restrict__ arm_conf,
                    const float* __restrict__ odm_loc,
                    const float* __restrict__ odm_conf,
                    const float* __restrict__ priors,
                    const float* __restrict__ ws_scores,
                    float* __restrict__ out) {
    __shared__ SMem sm;
    const int task = blockIdx.x;
    const int tid = threadIdx.x;

    // ---- extra blocks: zero the class-0 slabs, then exit ----
    if (task >= NTASK) {
        float* o = out + (size_t)(task - NTASK) * NCLS * TOPK * 5;
        for (int f = tid; f < TOPK * 5; f += NTHREADS) o[f] = 0.0f;
        return;
    }

    const int b = task / (NCLS - 1);
    const int c = task % (NCLS - 1) + 1;

    // ---- Phase 0: load my 32 scores into registers (single global pass) ----
    float s[32];
    if (PACKED) {
        const float4* sp = (const float4*)(ws_scores + (size_t)task * P_NUM);
        #pragma unroll
        for (int v = 0; v < 8; ++v) {
            int q = tid + 512 * v;            // 4080 float4s total
            float4 val = (q < 4080) ? sp[q] : make_float4(0.f, 0.f, 0.f, 0.f);
            s[4 * v + 0] = val.x; s[4 * v + 1] = val.y;
            s[4 * v + 2] = val.z; s[4 * v + 3] = val.w;
        }
    } else {
        const float* armc = arm_conf + (size_t)b * P_NUM * 2;
        const float* odmc = odm_conf + (size_t)b * P_NUM * NCLS;
        #pragma unroll 4
        for (int k = 0; k < 32; ++k) {
            int p = tid + 512 * k;
            float sc = 0.0f;
            if (p < P_NUM) {
                float o = armc[p * 2 + 1];
                sc = (o > OBJ_THR) ? odmc[p * NCLS + c] : 0.0f;
            }
            s[k] = sc;
        }
    }
    for (int i = tid; i < NBUCKET; i += NTHREADS) sm.u.a.hist[i] = 0u;
    if (tid == 0) sm.cand_count = 0;
    __syncthreads();

    // ---- Phase 1: histogram from registers ----
    #pragma unroll 4
    for (int k = 0; k < 32; ++k) {
        float sc = s[k];
        if (sc > CONF_THR) {
            int bk = (int)(sc * (float)NBUCKET);
            if (bk > NBUCKET - 1) bk = NBUCKET - 1;
            atomicAdd(&sm.u.a.hist[bk], 1u);
        }
    }
    __syncthreads();

    // ---- Phase 2: threshold bucket b* (two-level scan) ----
    {
        int s4 = 0;
        #pragma unroll
        for (int q = 0; q < 4; ++q) s4 += (int)sm.u.a.hist[tid * 4 + q];
        sm.u.a.csum[tid] = s4;
    }
    __syncthreads();
    if (tid < 64) {
        int g = 0;
        #pragma unroll
        for (int q = 0; q < 8; ++q) g += sm.u.a.csum[tid * 8 + q];
        sm.u.a.gsum[tid] = g;
    }
    __syncthreads();
    if (tid == 0) {
        int cum = 0, bstar = 0;
        for (int gg = 63; gg >= 0; --gg) {
            int gs = sm.u.a.gsum[gg];
            if (cum + gs >= TOPK) {
                for (int t = gg * 8 + 7; t >= gg * 8; --t) {
                    int cs = sm.u.a.csum[t];
                    if (cum + cs >= TOPK) {
                        for (int bk = t * 4 + 3; bk >= t * 4; --bk) {
                            cum += (int)sm.u.a.hist[bk];
                            if (cum >= TOPK) { bstar = bk; goto found; }
                        }
                    }
                    cum += cs;
                }
            }
            cum += gs;
        }
found:
        sm.bstar = bstar;   // total < 500 -> stays 0 -> gather all valid
    }
    __syncthreads();
    const int bstar = sm.bstar;

    // ---- Phase 3: gather candidates from registers ----
    #pragma unroll 4
    for (int k = 0; k < 32; ++k) {
        float sc = s[k];
        if (sc > CONF_THR) {
            int bk = (int)(sc * (float)NBUCKET);
            if (bk > NBUCKET - 1) bk = NBUCKET - 1;
            if (bk >= bstar) {
                int p;
                if (PACKED) p = 4 * (tid + 512 * (k >> 2)) + (k & 3);
                else        p = tid + 512 * k;
                int pos = atomicAdd(&sm.cand_count, 1);
                if (pos < CAND_CAP) {
                    u64 key = ((u64)__float_as_uint(sc) << 32) | (u32)(~(u32)p);
                    sm.u.a.keys[pos] = key;
                }
            }
        }
    }
    __syncthreads();
    int M = sm.cand_count; if (M > CAND_CAP) M = CAND_CAP;

    // ---- Phase 4: sort descending; common path = register bitonic (512) ----
    u64 v;
    if (__builtin_expect(M <= 512, 1)) {
        for (int i = M + tid; i < 512; i += NTHREADS) sm.u.a.keys[i] = 0ull;
        __syncthreads();
        v = sm.u.a.keys[tid];
        #pragma unroll
        for (int k = 2; k <= 512; k <<= 1) {
            for (int j = k >> 1; j > 0; j >>= 1) {
                u64 p;
                if (j >= 64) {                 // cross-wave: LDS exchange
                    sm.u.a.keys[tid] = v;
                    __syncthreads();
                    p = sm.u.a.keys[tid ^ j];
                    __syncthreads();
                } else {                        // in-wave: register shuffle
                    p = __shfl_xor((unsigned long long)v, j, 64);
                }
                const bool desc = ((tid & k) == 0);
                const bool lower = ((tid & j) == 0);
                const bool takeMax = (desc == lower);
                v = (takeMax == (v < p)) ? p : v;
            }
        }
    } else {
        // rare fallback: LDS bitonic on 1024
        for (int i = M + tid; i < CAND_CAP; i += NTHREADS) sm.u.a.keys[i] = 0ull;
        __syncthreads();
        for (int k = 2; k <= CAND_CAP; k <<= 1) {
            for (int j = k >> 1; j > 0; j >>= 1) {
                for (int t = tid; t < CAND_CAP; t += NTHREADS) {
                    int ixj = t ^ j;
                    if (ixj > t) {
                        u64 a = sm.u.a.keys[t];
                        u64 bb = sm.u.a.keys[ixj];
                        bool desc = ((t & k) == 0);
                        if (desc ? (a < bb) : (a > bb)) {
                            sm.u.a.keys[t] = bb;
                            sm.u.a.keys[ixj] = a;
                        }
                    }
                }
                __syncthreads();
            }
        }
        v = sm.u.a.keys[tid];
    }
    const int N = (M < TOPK) ? M : TOPK;

    // ---- Phase 5: cascaded decode, one row per thread from register key.
    //      Rows N..511 get sentinel boxes so phase 6 needs no bounds logic. ----
    if (tid < 8) sm.rowflag[tid] = 0ull;
    if (tid < N) {
        float sc = __uint_as_float((u32)(v >> 32));
        int p = (int)(~(u32)(v & 0xFFFFFFFFull));
        float4 pr = ((const float4*)priors)[p];
        float4 al = ((const float4*)(arm_loc + (size_t)b * P_NUM * 4))[p];
        float4 ol = ((const float4*)(odm_loc + (size_t)b * P_NUM * 4))[p];
        float cx = __fadd_rn(pr.x, __fmul_rn(__fmul_rn(al.x, 0.1f), pr.z));
        float cy = __fadd_rn(pr.y, __fmul_rn(__fmul_rn(al.y, 0.1f), pr.w));
        float w  = __fmul_rn(pr.z, (float)exp((double)__fmul_rn(al.z, 0.2f)));
        float h  = __fmul_rn(pr.w, (float)exp((double)__fmul_rn(al.w, 0.2f)));
        float mnx = __fsub_rn(cx, __fmul_rn(w, 0.5f));
        float mny = __fsub_rn(cy, __fmul_rn(h, 0.5f));
        float mxx = __fadd_rn(mnx, w);
        float mxy = __fadd_rn(mny, h);
        float dcx = __fmul_rn(__fadd_rn(mxx, mnx), 0.5f);
        float dcy = __fmul_rn(__fadd_rn(mxy, mny), 0.5f);
        float dw  = __fsub_rn(mxx, mnx);
        float dh  = __fsub_rn(mxy, mny);
        float cx2 = __fadd_rn(dcx, __fmul_rn(__fmul_rn(ol.x, 0.1f), dw));
        float cy2 = __fadd_rn(dcy, __fmul_rn(__fmul_rn(ol.y, 0.1f), dh));
        float w2  = __fmul_rn(dw, (float)exp((double)__fmul_rn(ol.z, 0.2f)));
        float h2  = __fmul_rn(dh, (float)exp((double)__fmul_rn(ol.w, 0.2f)));
        float x1 = __fsub_rn(cx2, __fmul_rn(w2, 0.5f));
        float y1 = __fsub_rn(cy2, __fmul_rn(h2, 0.5f));
        float x2 = __fadd_rn(x1, w2);
        float y2 = __fadd_rn(y1, h2);
        sm.sbox[tid] = make_float4(x1, y1, x2, y2);
        sm.sscore[tid] = sc;
        sm.sarea[tid] = __fmul_rn(__fsub_rn(x2, x1), __fsub_rn(y2, y1));
    } else {
        sm.sbox[tid] = make_float4(2.0f, 2.0f, -2.0f, -2.0f);  // inter == 0 vs anything
        sm.sscore[tid] = 0.0f;
        sm.sarea[tid] = 0.0f;
    }
    __syncthreads();   // keys (union) dead; tri region live from here

    // ---- Phase 6: suppression bitmask, register-broadcast scheme ----
    // One row per thread; wave w owns row-block perm{0,1,2,3,7,6,5,4}[w] so
    // each SIMD gets balanced block totals (9 blocks per SIMD). Columns are
    // loaded once per 64-j block into per-lane registers, then broadcast via
    // v_readlane (uniform jj) -> hot loop touches no memory at all.
    {
        const int wv = tid >> 6;
        const int lane = tid & 63;
        const int rb = (wv < 4) ? wv : (11 - wv);
        const int i = rb * 64 + lane;
        const bool rowvalid = (i < N);
        const float4 bi = sm.sbox[i];       // sentinel if invalid
        const float ai = sm.sarea[i];
        // triangular row base: block rb starts at 32*rb*(17-rb), stride (8-rb)
        const int rowBase = 32 * rb * (17 - rb) + lane * (8 - rb);
        const int nblk = (N + 63) >> 6;
        u64 anyb = 0ull;
        for (int jbk = rb; jbk < nblk; ++jbk) {
            const int j0 = jbk << 6;
            const float4 bj = sm.sbox[j0 + lane];   // per-lane, coalesced
            const float aj = sm.sarea[j0 + lane];
            int nearf = 0;
            u64 bits = iou_block<false>(bj, aj, bi, ai, i, j0, nearf);
            if (__builtin_expect(__any(nearf), 0)) {
                int dummy = 0;
                bits = iou_block<true>(bj, aj, bi, ai, i, j0, dummy);
            }
            if (rowvalid) sm.u.tri[rowBase + (jbk - rb)] = bits;
            anyb |= bits;
        }
        u64 flag = __ballot(anyb != 0ull);
        if (lane == 0) sm.rowflag[rb] = flag;
    }
    __syncthreads();

    // ---- Phase 7: greedy sweep — serial over flagged rows only, then
    //      parallel popcount-prefix compaction of survivors ----
    if (tid == 0) {
        u64 cur[8];
        #pragma unroll
        for (int w = 0; w < 8; ++w) {
            int lo = w * 64;
            cur[w] = (N >= lo + 64) ? ~0ull
                   : (N <= lo)      ? 0ull
                   : ((1ull << (N - lo)) - 1ull);
        }
        // tri[i] holds only words w >= i>>6 (bits j>i), so applying flagged
        // rows in ascending order (alive-checked) reproduces the greedy sweep.
        #pragma unroll
        for (int w = 0; w < 8; ++w) {
            u64 f = sm.rowflag[w];
            const int wb = 32 * w * (17 - w);
            const int wstride = 8 - w;
            while (f) {
                int bpos = __ffsll((unsigned long long)f) - 1;
                f &= f - 1;
                if ((cur[w] >> bpos) & 1ull) {
                    const u64* mrow = &sm.u.tri[wb + bpos * wstride];
                    #pragma unroll
                    for (int ww = w; ww < 8; ++ww)
                        cur[ww] &= ~mrow[ww - w];   // words >= nblk read junk; cur there is 0
                }
            }
        }
        int pref = 0;
        #pragma unroll
        for (int w = 0; w < 8; ++w) {
            sm.alive[w] = cur[w];
            sm.wordpref[w] = pref;
            pref += __popcll(cur[w]);
        }
        sm.n_emit = pref;
    }
    __syncthreads();
    if (tid < TOPK) {
        int w = tid >> 6, bpos = tid & 63;
        u64 aw = sm.alive[w];
        if ((aw >> bpos) & 1ull) {
            int pos = sm.wordpref[w] + __popcll(aw & ((1ull << bpos) - 1ull));
            sm.order[pos] = tid;
        }
    }
    __syncthreads();

    // ---- Phase 8: write full [500,5] slab (zeros beyond cnt) ----
    float* o = out + ((size_t)(b * NCLS + c)) * TOPK * 5;
    const int cnt = sm.n_emit;
    for (int f = tid; f < TOPK * 5; f += NTHREADS) {
        int k = f / 5;
        int r = f - k * 5;
        float val = 0.0f;
        if (k < cnt) {
            int i = sm.order[k];
            float4 bx = sm.sbox[i];
            val = (r == 0) ? sm.sscore[i]
                : (r == 1) ? bx.x
                : (r == 2) ? bx.y
                : (r == 3) ? bx.z
                :            bx.w;
        }
        o[f] = val;
    }
}

extern "C" void kernel_launch(void* const* d_in, const int* in_sizes, int n_in,
                              void* d_out, int out_size, void* d_ws, size_t ws_size,
                              hipStream_t stream) {
    const float* arm_loc  = (const float*)d_in[0];
    const float* arm_conf = (const float*)d_in[1];
    const float* odm_loc  = (const float*)d_in[2];
    const float* odm_conf = (const float*)d_in[3];
    const float* priors   = (const float*)d_in[4];
    float* out = (float*)d_out;

    const int grid = NTASK + B_NUM;   // 640 tasks + 32 class-0 zeroers
    const size_t need = (size_t)NTASK * P_NUM * sizeof(float); // 41.8 MB
    if (ws_size >= need) {
        float* wsf = (float*)d_ws;
        mask_transpose<<<B_NUM * 64, 256, 0, stream>>>(arm_conf, odm_conf, wsf);
        refinedet_main<true><<<grid, NTHREADS, 0, stream>>>(
            arm_loc, arm_conf, odm_loc, odm_conf, priors, wsf, out);
    } else {
        refinedet_main<false><<<grid, NTHREADS, 0, stream>>>(
            arm_loc, arm_conf, odm_loc, odm_conf, priors, nullptr, out);
    }
}

// Round 3
// 260.595 us; speedup vs baseline: 1.0280x; 1.0280x over previous
//
#include <hip/hip_runtime.h>
#include <math.h>

#define P_NUM   16320
#define B_NUM   32
#define NCLS    21
#define TOPK    500
#define CONF_THR 0.01f
#define NMS_THR  0.45f
#define OBJ_THR  0.01f
#define NBUCKET 2048
#define CAND_CAP 1024
#define NTHREADS 512
#define CHUNK   256
#define NTASK   (B_NUM * (NCLS - 1))
#define TRI_WORDS 2304       // sum_{b=0..7} 64*(8-b)
#define NEAR_EPS 1e-6f       // guard zone ~2^-25 rel; 1e-6 is safely wider

typedef unsigned long long u64;
typedef unsigned int u32;

struct SMemA {
    u32 hist[NBUCKET];    // 8192 B
    int csum[NTHREADS];   // 2048 B
    int gsum[64];         // 256 B
    u64 keys[CAND_CAP];   // 8192 B  (also cross-wave sort exchange buffer)
};

struct SMem {
    union {
        SMemA a;          // phases 0-4
        u64 tri[TRI_WORDS]; // 18432 B triangular mask (phases 6-7)
    } u;                  // 18688 B
    float4 sbox[512];     // 8192 B (padded to 512 with sentinels)
    float  sscore[512];   // 2048 B
    float  sarea[512];    // 2048 B
    int    order[512];    // 2048 B
    u64    rowflag[8];
    u64    alive[8];
    int    wordpref[8];
    int    cand_count;
    int    bstar;
    int    n_emit;
};                        // ~33.2 KB (grid is occupancy limiter, not LDS)

// ---- mask + transpose odm_conf into per-task contiguous score arrays ----
__global__ __launch_bounds__(256)
void mask_transpose(const float* __restrict__ arm_conf,
                    const float* __restrict__ odm_conf,
                    float* __restrict__ ws) {
    __shared__ float tile[NCLS][CHUNK + 1];
    __shared__ float obj[CHUNK];
    const int blk = blockIdx.x;
    const int b = blk >> 6;
    const int ch = blk & 63;
    const int p0 = ch * CHUNK;
    const int np = min(CHUNK, P_NUM - p0);    // 256, last chunk 192
    const int tid = threadIdx.x;

    const float4* oc4 = (const float4*)(odm_conf + ((size_t)b * P_NUM + p0) * NCLS);
    const float* ac = arm_conf + ((size_t)b * P_NUM + p0) * 2;
    const int count4 = (np * NCLS) / 4;       // 1344 or 1008
    for (int q = tid; q < count4; q += 256) {
        float4 v = oc4[q];                    // coalesced 16B
        int f = 4 * q;
        {
            int p = f / NCLS;       int cc = f - p * NCLS;       tile[cc][p] = v.x;
        }
        {
            int p = (f+1) / NCLS;   int cc = (f+1) - p * NCLS;   tile[cc][p] = v.y;
        }
        {
            int p = (f+2) / NCLS;   int cc = (f+2) - p * NCLS;   tile[cc][p] = v.z;
        }
        {
            int p = (f+3) / NCLS;   int cc = (f+3) - p * NCLS;   tile[cc][p] = v.w;
        }
    }
    if (tid < np) obj[tid] = ac[tid * 2 + 1];
    __syncthreads();

    const int nv = np / 4;                    // 64 or 48
    const int total = 20 * nv;
    for (int i = tid; i < total; i += 256) {
        int cc = i / nv;                      // 0..19 -> class cc+1
        int pp = i - cc * nv;
        const float* t = &tile[cc + 1][4 * pp];
        float4 ov = make_float4(
            (obj[4*pp+0] > OBJ_THR) ? t[0] : 0.0f,
            (obj[4*pp+1] > OBJ_THR) ? t[1] : 0.0f,
            (obj[4*pp+2] > OBJ_THR) ? t[2] : 0.0f,
            (obj[4*pp+3] > OBJ_THR) ? t[3] : 0.0f);
        float4* w4 = (float4*)(ws + ((size_t)(b * 20 + cc)) * P_NUM + p0);
        w4[pp] = ov;                          // coalesced 16B store
    }
}

// wave-uniform broadcast of lane jj's value (v_readlane -> SGPR, pure VALU)
__device__ __forceinline__ float rl(float x, int l) {
    return __int_as_float(__builtin_amdgcn_readlane(__float_as_int(x), l));
}

// One 64-column IoU block for this lane's row. Branchless hot path; EXACT
// variant replicates the reference's fl(inter/denom) > 0.45f decision and is
// run only when a lane lands in the fma-vs-div disagreement guard zone.
template <bool EXACT>
__device__ __forceinline__ u64 iou_block(float4 bj, float ajv, float4 bi, float ai,
                                         int i, int j0, int& nearf) {
    u64 bits = 0ull;
    #pragma unroll 16
    for (int jj = 0; jj < 64; ++jj) {
        float sx1 = rl(bj.x, jj);
        float sy1 = rl(bj.y, jj);
        float sx2 = rl(bj.z, jj);
        float sy2 = rl(bj.w, jj);
        float aj  = rl(ajv, jj);
        float xx1 = fmaxf(sx1, bi.x);
        float yy1 = fmaxf(sy1, bi.y);
        float xx2 = fminf(sx2, bi.z);
        float yy2 = fminf(sy2, bi.w);
        float iw = fmaxf(__fsub_rn(xx2, xx1), 0.0f);
        float ih = fmaxf(__fsub_rn(yy2, yy1), 0.0f);
        float inter = __fmul_rn(iw, ih);
        float denom = __fadd_rn(__fsub_rn(aj, inter), ai);   // (aj - inter) + ai, ref order
        bool sup;
        if (EXACT) {
            sup = (__fdiv_rn(inter, denom) > NMS_THR);
        } else {
            // sign(fma) == sign(inter - 0.45*denom) exactly (single rounding).
            float d = __builtin_fmaf(-NMS_THR, denom, inter);
            sup = (d > 0.0f);
            nearf |= (int)((inter > 0.0f) && (fabsf(d) <= __fmul_rn(denom, NEAR_EPS)));
        }
        bool on = sup && ((j0 + jj) > i);
        // shift-insert: element jj ends at bit jj after 64 steps
        bits = (bits >> 1) | (on ? 0x8000000000000000ull : 0ull);
    }
    return bits;
}

template <bool PACKED>
__global__ __launch_bounds__(NTHREADS)
void refinedet_main(const float* __restrict__ arm_loc,
                    const float* __restrict__ arm_conf,
                    const float* __restrict__ odm_loc,
                    const float* __restrict__ odm_conf,
                    const float* __restrict__ priors,
                    const float* __restrict__ ws_scores,
                    float* __restrict__ out) {
    __shared__ SMem sm;
    const int task = blockIdx.x;
    const int tid = threadIdx.x;

    // ---- extra blocks: zero the class-0 slabs, then exit ----
    if (task >= NTASK) {
        float* o = out + (size_t)(task - NTASK) * NCLS * TOPK * 5;
        for (int f = tid; f < TOPK * 5; f += NTHREADS) o[f] = 0.0f;
        return;
    }

    const int b = task / (NCLS - 1);
    const int c = task % (NCLS - 1) + 1;

    // ---- Phase 0: load my 32 scores into registers (single global pass) ----
    float s[32];
    if (PACKED) {
        const float4* sp = (const float4*)(ws_scores + (size_t)task * P_NUM);
        #pragma unroll
        for (int v = 0; v < 8; ++v) {
            int q = tid + 512 * v;            // 4080 float4s total
            float4 val = (q < 4080) ? sp[q] : make_float4(0.f, 0.f, 0.f, 0.f);
            s[4 * v + 0] = val.x; s[4 * v + 1] = val.y;
            s[4 * v + 2] = val.z; s[4 * v + 3] = val.w;
        }
    } else {
        const float* armc = arm_conf + (size_t)b * P_NUM * 2;
        const float* odmc = odm_conf + (size_t)b * P_NUM * NCLS;
        #pragma unroll 4
        for (int k = 0; k < 32; ++k) {
            int p = tid + 512 * k;
            float sc = 0.0f;
            if (p < P_NUM) {
                float o = armc[p * 2 + 1];
                sc = (o > OBJ_THR) ? odmc[p * NCLS + c] : 0.0f;
            }
            s[k] = sc;
        }
    }
    for (int i = tid; i < NBUCKET; i += NTHREADS) sm.u.a.hist[i] = 0u;
    if (tid == 0) sm.cand_count = 0;
    __syncthreads();

    // ---- Phase 1: histogram from registers ----
    #pragma unroll 4
    for (int k = 0; k < 32; ++k) {
        float sc = s[k];
        if (sc > CONF_THR) {
            int bk = (int)(sc * (float)NBUCKET);
            if (bk > NBUCKET - 1) bk = NBUCKET - 1;
            atomicAdd(&sm.u.a.hist[bk], 1u);
        }
    }
    __syncthreads();

    // ---- Phase 2: threshold bucket b* (two-level scan) ----
    {
        int s4 = 0;
        #pragma unroll
        for (int q = 0; q < 4; ++q) s4 += (int)sm.u.a.hist[tid * 4 + q];
        sm.u.a.csum[tid] = s4;
    }
    __syncthreads();
    if (tid < 64) {
        int g = 0;
        #pragma unroll
        for (int q = 0; q < 8; ++q) g += sm.u.a.csum[tid * 8 + q];
        sm.u.a.gsum[tid] = g;
    }
    __syncthreads();
    if (tid == 0) {
        int cum = 0, bstar = 0;
        for (int gg = 63; gg >= 0; --gg) {
            int gs = sm.u.a.gsum[gg];
            if (cum + gs >= TOPK) {
                for (int t = gg * 8 + 7; t >= gg * 8; --t) {
                    int cs = sm.u.a.csum[t];
                    if (cum + cs >= TOPK) {
                        for (int bk = t * 4 + 3; bk >= t * 4; --bk) {
                            cum += (int)sm.u.a.hist[bk];
                            if (cum >= TOPK) { bstar = bk; goto found; }
                        }
                    }
                    cum += cs;
                }
            }
            cum += gs;
        }
found:
        sm.bstar = bstar;   // total < 500 -> stays 0 -> gather all valid
    }
    __syncthreads();
    const int bstar = sm.bstar;

    // ---- Phase 3: gather candidates from registers ----
    #pragma unroll 4
    for (int k = 0; k < 32; ++k) {
        float sc = s[k];
        if (sc > CONF_THR) {
            int bk = (int)(sc * (float)NBUCKET);
            if (bk > NBUCKET - 1) bk = NBUCKET - 1;
            if (bk >= bstar) {
                int p;
                if (PACKED) p = 4 * (tid + 512 * (k >> 2)) + (k & 3);
                else        p = tid + 512 * k;
                int pos = atomicAdd(&sm.cand_count, 1);
                if (pos < CAND_CAP) {
                    u64 key = ((u64)__float_as_uint(sc) << 32) | (u32)(~(u32)p);
                    sm.u.a.keys[pos] = key;
                }
            }
        }
    }
    __syncthreads();
    int M = sm.cand_count; if (M > CAND_CAP) M = CAND_CAP;

    // ---- Phase 4: sort descending; common path = register bitonic (512) ----
    u64 v;
    if (__builtin_expect(M <= 512, 1)) {
        for (int i = M + tid; i < 512; i += NTHREADS) sm.u.a.keys[i] = 0ull;
        __syncthreads();
        v = sm.u.a.keys[tid];
        #pragma unroll
        for (int k = 2; k <= 512; k <<= 1) {
            for (int j = k >> 1; j > 0; j >>= 1) {
                u64 p;
                if (j >= 64) {                 // cross-wave: LDS exchange
                    sm.u.a.keys[tid] = v;
                    __syncthreads();
                    p = sm.u.a.keys[tid ^ j];
                    __syncthreads();
                } else {                        // in-wave: register shuffle
                    p = __shfl_xor((unsigned long long)v, j, 64);
                }
                const bool desc = ((tid & k) == 0);
                const bool lower = ((tid & j) == 0);
                const bool takeMax = (desc == lower);
                v = (takeMax == (v < p)) ? p : v;
            }
        }
    } else {
        // rare fallback: LDS bitonic on 1024
        for (int i = M + tid; i < CAND_CAP; i += NTHREADS) sm.u.a.keys[i] = 0ull;
        __syncthreads();
        for (int k = 2; k <= CAND_CAP; k <<= 1) {
            for (int j = k >> 1; j > 0; j >>= 1) {
                for (int t = tid; t < CAND_CAP; t += NTHREADS) {
                    int ixj = t ^ j;
                    if (ixj > t) {
                        u64 a = sm.u.a.keys[t];
                        u64 bb = sm.u.a.keys[ixj];
                        bool desc = ((t & k) == 0);
                        if (desc ? (a < bb) : (a > bb)) {
                            sm.u.a.keys[t] = bb;
                            sm.u.a.keys[ixj] = a;
                        }
                    }
                }
                __syncthreads();
            }
        }
        v = sm.u.a.keys[tid];
    }
    const int N = (M < TOPK) ? M : TOPK;

    // ---- Phase 5: cascaded decode, one row per thread from register key.
    //      Rows N..511 get sentinel boxes so phase 6 needs no bounds logic. ----
    if (tid < 8) sm.rowflag[tid] = 0ull;
    if (tid < N) {
        float sc = __uint_as_float((u32)(v >> 32));
        int p = (int)(~(u32)(v & 0xFFFFFFFFull));
        float4 pr = ((const float4*)priors)[p];
        float4 al = ((const float4*)(arm_loc + (size_t)b * P_NUM * 4))[p];
        float4 ol = ((const float4*)(odm_loc + (size_t)b * P_NUM * 4))[p];
        float cx = __fadd_rn(pr.x, __fmul_rn(__fmul_rn(al.x, 0.1f), pr.z));
        float cy = __fadd_rn(pr.y, __fmul_rn(__fmul_rn(al.y, 0.1f), pr.w));
        float w  = __fmul_rn(pr.z, (float)exp((double)__fmul_rn(al.z, 0.2f)));
        float h  = __fmul_rn(pr.w, (float)exp((double)__fmul_rn(al.w, 0.2f)));
        float mnx = __fsub_rn(cx, __fmul_rn(w, 0.5f));
        float mny = __fsub_rn(cy, __fmul_rn(h, 0.5f));
        float mxx = __fadd_rn(mnx, w);
        float mxy = __fadd_rn(mny, h);
        float dcx = __fmul_rn(__fadd_rn(mxx, mnx), 0.5f);
        float dcy = __fmul_rn(__fadd_rn(mxy, mny), 0.5f);
        float dw  = __fsub_rn(mxx, mnx);
        float dh  = __fsub_rn(mxy, mny);
        float cx2 = __fadd_rn(dcx, __fmul_rn(__fmul_rn(ol.x, 0.1f), dw));
        float cy2 = __fadd_rn(dcy, __fmul_rn(__fmul_rn(ol.y, 0.1f), dh));
        float w2  = __fmul_rn(dw, (float)exp((double)__fmul_rn(ol.z, 0.2f)));
        float h2  = __fmul_rn(dh, (float)exp((double)__fmul_rn(ol.w, 0.2f)));
        float x1 = __fsub_rn(cx2, __fmul_rn(w2, 0.5f));
        float y1 = __fsub_rn(cy2, __fmul_rn(h2, 0.5f));
        float x2 = __fadd_rn(x1, w2);
        float y2 = __fadd_rn(y1, h2);
        sm.sbox[tid] = make_float4(x1, y1, x2, y2);
        sm.sscore[tid] = sc;
        sm.sarea[tid] = __fmul_rn(__fsub_rn(x2, x1), __fsub_rn(y2, y1));
    } else {
        sm.sbox[tid] = make_float4(2.0f, 2.0f, -2.0f, -2.0f);  // inter == 0 vs anything
        sm.sscore[tid] = 0.0f;
        sm.sarea[tid] = 0.0f;
    }
    __syncthreads();   // keys (union) dead; tri region live from here

    // ---- Phase 6: suppression bitmask, register-broadcast scheme ----
    // One row per thread; wave w owns row-block perm{0,1,2,3,7,6,5,4}[w] so
    // each SIMD gets balanced block totals (9 blocks per SIMD). Columns are
    // loaded once per 64-j block into per-lane registers, then broadcast via
    // v_readlane (uniform jj) -> hot loop touches no memory at all.
    {
        const int wv = tid >> 6;
        const int lane = tid & 63;
        const int rb = (wv < 4) ? wv : (11 - wv);
        const int i = rb * 64 + lane;
        const bool rowvalid = (i < N);
        const float4 bi = sm.sbox[i];       // sentinel if invalid
        const float ai = sm.sarea[i];
        // triangular row base: block rb starts at 32*rb*(17-rb), stride (8-rb)
        const int rowBase = 32 * rb * (17 - rb) + lane * (8 - rb);
        const int nblk = (N + 63) >> 6;
        u64 anyb = 0ull;
        for (int jbk = rb; jbk < nblk; ++jbk) {
            const int j0 = jbk << 6;
            const float4 bj = sm.sbox[j0 + lane];   // per-lane, coalesced
            const float aj = sm.sarea[j0 + lane];
            int nearf = 0;
            u64 bits = iou_block<false>(bj, aj, bi, ai, i, j0, nearf);
            if (__builtin_expect(__any(nearf), 0)) {
                int dummy = 0;
                bits = iou_block<true>(bj, aj, bi, ai, i, j0, dummy);
            }
            if (rowvalid) sm.u.tri[rowBase + (jbk - rb)] = bits;
            anyb |= bits;
        }
        u64 flag = __ballot(anyb != 0ull);
        if (lane == 0) sm.rowflag[rb] = flag;
    }
    __syncthreads();

    // ---- Phase 7: greedy sweep — serial over flagged rows only, then
    //      parallel popcount-prefix compaction of survivors ----
    if (tid == 0) {
        u64 cur[8];
        #pragma unroll
        for (int w = 0; w < 8; ++w) {
            int lo = w * 64;
            cur[w] = (N >= lo + 64) ? ~0ull
                   : (N <= lo)      ? 0ull
                   : ((1ull << (N - lo)) - 1ull);
        }
        // tri[i] holds only words w >= i>>6 (bits j>i), so applying flagged
        // rows in ascending order (alive-checked) reproduces the greedy sweep.
        #pragma unroll
        for (int w = 0; w < 8; ++w) {
            u64 f = sm.rowflag[w];
            const int wb = 32 * w * (17 - w);
            const int wstride = 8 - w;
            while (f) {
                int bpos = __ffsll((unsigned long long)f) - 1;
                f &= f - 1;
                if ((cur[w] >> bpos) & 1ull) {
                    const u64* mrow = &sm.u.tri[wb + bpos * wstride];
                    #pragma unroll
                    for (int ww = w; ww < 8; ++ww)
                        cur[ww] &= ~mrow[ww - w];   // words >= nblk read junk; cur there is 0
                }
            }
        }
        int pref = 0;
        #pragma unroll
        for (int w = 0; w < 8; ++w) {
            sm.alive[w] = cur[w];
            sm.wordpref[w] = pref;
            pref += __popcll(cur[w]);
        }
        sm.n_emit = pref;
    }
    __syncthreads();
    if (tid < TOPK) {
        int w = tid >> 6, bpos = tid & 63;
        u64 aw = sm.alive[w];
        if ((aw >> bpos) & 1ull) {
            int pos = sm.wordpref[w] + __popcll(aw & ((1ull << bpos) - 1ull));
            sm.order[pos] = tid;
        }
    }
    __syncthreads();

    // ---- Phase 8: write full [500,5] slab (zeros beyond cnt) ----
    float* o = out + ((size_t)(b * NCLS + c)) * TOPK * 5;
    const int cnt = sm.n_emit;
    for (int f = tid; f < TOPK * 5; f += NTHREADS) {
        int k = f / 5;
        int r = f - k * 5;
        float val = 0.0f;
        if (k < cnt) {
            int i = sm.order[k];
            float4 bx = sm.sbox[i];
            val = (r == 0) ? sm.sscore[i]
                : (r == 1) ? bx.x
                : (r == 2) ? bx.y
                : (r == 3) ? bx.z
                :            bx.w;
        }
        o[f] = val;
    }
}

extern "C" void kernel_launch(void* const* d_in, const int* in_sizes, int n_in,
                              void* d_out, int out_size, void* d_ws, size_t ws_size,
                              hipStream_t stream) {
    const float* arm_loc  = (const float*)d_in[0];
    const float* arm_conf = (const float*)d_in[1];
    const float* odm_loc  = (const float*)d_in[2];
    const float* odm_conf = (const float*)d_in[3];
    const float* priors   = (const float*)d_in[4];
    float* out = (float*)d_out;

    const int grid = NTASK + B_NUM;   // 640 tasks + 32 class-0 zeroers
    const size_t need = (size_t)NTASK * P_NUM * sizeof(float); // 41.8 MB
    if (ws_size >= need) {
        float* wsf = (float*)d_ws;
        mask_transpose<<<B_NUM * 64, 256, 0, stream>>>(arm_conf, odm_conf, wsf);
        refinedet_main<true><<<grid, NTHREADS, 0, stream>>>(
            arm_loc, arm_conf, odm_loc, odm_conf, priors, wsf, out);
    } else {
        refinedet_main<false><<<grid, NTHREADS, 0, stream>>>(
            arm_loc, arm_conf, odm_loc, odm_conf, priors, nullptr, out);
    }
}

// Round 4
// 214.758 us; speedup vs baseline: 1.2474x; 1.2134x over previous
//
#include <hip/hip_runtime.h>
#include <math.h>

#define P_NUM   16320
#define B_NUM   32
#define NCLS    21
#define TOPK    500
#define CONF_THR 0.01f
#define NMS_THR  0.45f
#define OBJ_THR  0.01f
#define NBUCKET 2048
#define CAND_CAP 1024
#define NTHREADS 512
#define CHUNK   256
#define NTASK   (B_NUM * (NCLS - 1))
#define TRI_WORDS 2304       // sum_{b=0..7} 64*(8-b)
#define NEAR_EPS 1e-6f       // guard zone; fma-vs-div disagreement needs ~3e-8 rel

typedef unsigned long long u64;
typedef unsigned int u32;

struct SMemA {
    u32 hist[NBUCKET];    // 8192 B
    int csum[NTHREADS];   // 2048 B
    int gsum[64];         // 256 B
    u64 keys[CAND_CAP];   // 8192 B  (also cross-wave sort exchange buffer)
};

struct SMem {
    union {
        SMemA a;            // phases 0-4
        u64 tri[TRI_WORDS]; // 18432 B triangular mask (phases 6-7)
    } u;
    float4 sbox[512];     // 8192 B (padded to 512 with sentinels)
    float  sscore[512];   // 2048 B
    float  sarea[512];    // 2048 B
    int    order[512];    // 2048 B
    u64    rowflag[8];
    u64    alive[8];
    int    wordpref[8];
    int    cand_count;
    int    bstar;
    int    n_emit;
};                        // ~33.2 KB

// ---- mask + transpose odm_conf into per-task contiguous score arrays ----
__global__ __launch_bounds__(256)
void mask_transpose(const float* __restrict__ arm_conf,
                    const float* __restrict__ odm_conf,
                    float* __restrict__ ws) {
    __shared__ float tile[NCLS][CHUNK + 1];
    __shared__ float obj[CHUNK];
    const int blk = blockIdx.x;
    const int b = blk >> 6;
    const int ch = blk & 63;
    const int p0 = ch * CHUNK;
    const int np = min(CHUNK, P_NUM - p0);    // 256, last chunk 192
    const int tid = threadIdx.x;

    const float4* oc4 = (const float4*)(odm_conf + ((size_t)b * P_NUM + p0) * NCLS);
    const float* ac = arm_conf + ((size_t)b * P_NUM + p0) * 2;
    const int count4 = (np * NCLS) / 4;       // 1344 or 1008
    for (int q = tid; q < count4; q += 256) {
        float4 v = oc4[q];                    // coalesced 16B
        int f = 4 * q;
        {
            int p = f / NCLS;       int cc = f - p * NCLS;       tile[cc][p] = v.x;
        }
        {
            int p = (f+1) / NCLS;   int cc = (f+1) - p * NCLS;   tile[cc][p] = v.y;
        }
        {
            int p = (f+2) / NCLS;   int cc = (f+2) - p * NCLS;   tile[cc][p] = v.z;
        }
        {
            int p = (f+3) / NCLS;   int cc = (f+3) - p * NCLS;   tile[cc][p] = v.w;
        }
    }
    if (tid < np) obj[tid] = ac[tid * 2 + 1];
    __syncthreads();

    const int nv = np / 4;                    // 64 or 48
    const int total = 20 * nv;
    for (int i = tid; i < total; i += 256) {
        int cc = i / nv;                      // 0..19 -> class cc+1
        int pp = i - cc * nv;
        const float* t = &tile[cc + 1][4 * pp];
        float4 ov = make_float4(
            (obj[4*pp+0] > OBJ_THR) ? t[0] : 0.0f,
            (obj[4*pp+1] > OBJ_THR) ? t[1] : 0.0f,
            (obj[4*pp+2] > OBJ_THR) ? t[2] : 0.0f,
            (obj[4*pp+3] > OBJ_THR) ? t[3] : 0.0f);
        float4* w4 = (float4*)(ws + ((size_t)(b * 20 + cc)) * P_NUM + p0);
        w4[pp] = ov;                          // coalesced 16B store
    }
}

// 64-bit readlane (lane index may be SGPR)
__device__ __forceinline__ u64 rl64(u64 x, int l) {
    u32 lo = (u32)__builtin_amdgcn_readlane((int)(u32)x, l);
    u32 hi = (u32)__builtin_amdgcn_readlane((int)(u32)(x >> 32), l);
    return ((u64)hi << 32) | lo;
}

template <bool PACKED>
__global__ __launch_bounds__(NTHREADS)
void refinedet_main(const float* __restrict__ arm_loc,
                    const float* __restrict__ arm_conf,
                    const float* __restrict__ odm_loc,
                    const float* __restrict__ odm_conf,
                    const float* __restrict__ priors,
                    const float* __restrict__ ws_scores,
                    float* __restrict__ out) {
    __shared__ SMem sm;
    const int task = blockIdx.x;
    const int tid = threadIdx.x;

    // ---- extra blocks: zero the class-0 slabs, then exit ----
    if (task >= NTASK) {
        float* o = out + (size_t)(task - NTASK) * NCLS * TOPK * 5;
        for (int f = tid; f < TOPK * 5; f += NTHREADS) o[f] = 0.0f;
        return;
    }

    const int b = task / (NCLS - 1);
    const int c = task % (NCLS - 1) + 1;

    // ---- Phase 0: load my 32 scores into registers (single global pass) ----
    float s[32];
    if (PACKED) {
        const float4* sp = (const float4*)(ws_scores + (size_t)task * P_NUM);
        #pragma unroll
        for (int v = 0; v < 8; ++v) {
            int q = tid + 512 * v;            // 4080 float4s total
            float4 val = (q < 4080) ? sp[q] : make_float4(0.f, 0.f, 0.f, 0.f);
            s[4 * v + 0] = val.x; s[4 * v + 1] = val.y;
            s[4 * v + 2] = val.z; s[4 * v + 3] = val.w;
        }
    } else {
        const float* armc = arm_conf + (size_t)b * P_NUM * 2;
        const float* odmc = odm_conf + (size_t)b * P_NUM * NCLS;
        #pragma unroll 4
        for (int k = 0; k < 32; ++k) {
            int p = tid + 512 * k;
            float sc = 0.0f;
            if (p < P_NUM) {
                float o = armc[p * 2 + 1];
                sc = (o > OBJ_THR) ? odmc[p * NCLS + c] : 0.0f;
            }
            s[k] = sc;
        }
    }
    for (int i = tid; i < NBUCKET; i += NTHREADS) sm.u.a.hist[i] = 0u;
    if (tid == 0) sm.cand_count = 0;
    __syncthreads();

    // ---- Phase 1: histogram from registers ----
    #pragma unroll 4
    for (int k = 0; k < 32; ++k) {
        float sc = s[k];
        if (sc > CONF_THR) {
            int bk = (int)(sc * (float)NBUCKET);
            if (bk > NBUCKET - 1) bk = NBUCKET - 1;
            atomicAdd(&sm.u.a.hist[bk], 1u);
        }
    }
    __syncthreads();

    // ---- Phase 2: threshold bucket b* (two-level scan) ----
    {
        int s4 = 0;
        #pragma unroll
        for (int q = 0; q < 4; ++q) s4 += (int)sm.u.a.hist[tid * 4 + q];
        sm.u.a.csum[tid] = s4;
    }
    __syncthreads();
    if (tid < 64) {
        int g = 0;
        #pragma unroll
        for (int q = 0; q < 8; ++q) g += sm.u.a.csum[tid * 8 + q];
        sm.u.a.gsum[tid] = g;
    }
    __syncthreads();
    if (tid == 0) {
        int cum = 0, bstar = 0;
        for (int gg = 63; gg >= 0; --gg) {
            int gs = sm.u.a.gsum[gg];
            if (cum + gs >= TOPK) {
                for (int t = gg * 8 + 7; t >= gg * 8; --t) {
                    int cs = sm.u.a.csum[t];
                    if (cum + cs >= TOPK) {
                        for (int bk = t * 4 + 3; bk >= t * 4; --bk) {
                            cum += (int)sm.u.a.hist[bk];
                            if (cum >= TOPK) { bstar = bk; goto found; }
                        }
                    }
                    cum += cs;
                }
            }
            cum += gs;
        }
found:
        sm.bstar = bstar;   // total < 500 -> stays 0 -> gather all valid
    }
    __syncthreads();
    const int bstar = sm.bstar;

    // ---- Phase 3: gather candidates from registers ----
    #pragma unroll 4
    for (int k = 0; k < 32; ++k) {
        float sc = s[k];
        if (sc > CONF_THR) {
            int bk = (int)(sc * (float)NBUCKET);
            if (bk > NBUCKET - 1) bk = NBUCKET - 1;
            if (bk >= bstar) {
                int p;
                if (PACKED) p = 4 * (tid + 512 * (k >> 2)) + (k & 3);
                else        p = tid + 512 * k;
                int pos = atomicAdd(&sm.cand_count, 1);
                if (pos < CAND_CAP) {
                    u64 key = ((u64)__float_as_uint(sc) << 32) | (u32)(~(u32)p);
                    sm.u.a.keys[pos] = key;
                }
            }
        }
    }
    __syncthreads();
    int M = sm.cand_count; if (M > CAND_CAP) M = CAND_CAP;

    // ---- Phase 4: sort descending; common path = register bitonic (512) ----
    u64 v;
    if (__builtin_expect(M <= 512, 1)) {
        for (int i = M + tid; i < 512; i += NTHREADS) sm.u.a.keys[i] = 0ull;
        __syncthreads();
        v = sm.u.a.keys[tid];
        #pragma unroll
        for (int k = 2; k <= 512; k <<= 1) {
            for (int j = k >> 1; j > 0; j >>= 1) {
                u64 p;
                if (j >= 64) {                 // cross-wave: LDS exchange
                    sm.u.a.keys[tid] = v;
                    __syncthreads();
                    p = sm.u.a.keys[tid ^ j];
                    __syncthreads();
                } else {                        // in-wave: register shuffle
                    p = __shfl_xor((unsigned long long)v, j, 64);
                }
                const bool desc = ((tid & k) == 0);
                const bool lower = ((tid & j) == 0);
                const bool takeMax = (desc == lower);
                v = (takeMax == (v < p)) ? p : v;
            }
        }
    } else {
        // rare fallback: LDS bitonic on 1024
        for (int i = M + tid; i < CAND_CAP; i += NTHREADS) sm.u.a.keys[i] = 0ull;
        __syncthreads();
        for (int k = 2; k <= CAND_CAP; k <<= 1) {
            for (int j = k >> 1; j > 0; j >>= 1) {
                for (int t = tid; t < CAND_CAP; t += NTHREADS) {
                    int ixj = t ^ j;
                    if (ixj > t) {
                        u64 a = sm.u.a.keys[t];
                        u64 bb = sm.u.a.keys[ixj];
                        bool desc = ((t & k) == 0);
                        if (desc ? (a < bb) : (a > bb)) {
                            sm.u.a.keys[t] = bb;
                            sm.u.a.keys[ixj] = a;
                        }
                    }
                }
                __syncthreads();
            }
        }
        v = sm.u.a.keys[tid];
    }
    const int N = (M < TOPK) ? M : TOPK;

    // ---- Phase 5: cascaded decode, one row per thread from register key.
    //      Rows N..511 get sentinel boxes so phase 6 needs no bounds logic. ----
    if (tid < 8) sm.rowflag[tid] = 0ull;
    if (tid < N) {
        float sc = __uint_as_float((u32)(v >> 32));
        int p = (int)(~(u32)(v & 0xFFFFFFFFull));
        float4 pr = ((const float4*)priors)[p];
        float4 al = ((const float4*)(arm_loc + (size_t)b * P_NUM * 4))[p];
        float4 ol = ((const float4*)(odm_loc + (size_t)b * P_NUM * 4))[p];
        float cx = __fadd_rn(pr.x, __fmul_rn(__fmul_rn(al.x, 0.1f), pr.z));
        float cy = __fadd_rn(pr.y, __fmul_rn(__fmul_rn(al.y, 0.1f), pr.w));
        float w  = __fmul_rn(pr.z, (float)exp((double)__fmul_rn(al.z, 0.2f)));
        float h  = __fmul_rn(pr.w, (float)exp((double)__fmul_rn(al.w, 0.2f)));
        float mnx = __fsub_rn(cx, __fmul_rn(w, 0.5f));
        float mny = __fsub_rn(cy, __fmul_rn(h, 0.5f));
        float mxx = __fadd_rn(mnx, w);
        float mxy = __fadd_rn(mny, h);
        float dcx = __fmul_rn(__fadd_rn(mxx, mnx), 0.5f);
        float dcy = __fmul_rn(__fadd_rn(mxy, mny), 0.5f);
        float dw  = __fsub_rn(mxx, mnx);
        float dh  = __fsub_rn(mxy, mny);
        float cx2 = __fadd_rn(dcx, __fmul_rn(__fmul_rn(ol.x, 0.1f), dw));
        float cy2 = __fadd_rn(dcy, __fmul_rn(__fmul_rn(ol.y, 0.1f), dh));
        float w2  = __fmul_rn(dw, (float)exp((double)__fmul_rn(ol.z, 0.2f)));
        float h2  = __fmul_rn(dh, (float)exp((double)__fmul_rn(ol.w, 0.2f)));
        float x1 = __fsub_rn(cx2, __fmul_rn(w2, 0.5f));
        float y1 = __fsub_rn(cy2, __fmul_rn(h2, 0.5f));
        float x2 = __fadd_rn(x1, w2);
        float y2 = __fadd_rn(y1, h2);
        sm.sbox[tid] = make_float4(x1, y1, x2, y2);
        sm.sscore[tid] = sc;
        sm.sarea[tid] = __fmul_rn(__fsub_rn(x2, x1), __fsub_rn(y2, y1));
    } else {
        sm.sbox[tid] = make_float4(2.0f, 2.0f, -2.0f, -2.0f);  // inter == 0 vs anything; area 16 > 0
        sm.sscore[tid] = 0.0f;
        sm.sarea[tid] = 16.0f;
    }
    __syncthreads();   // keys (union) dead; tri region live from here

    // ---- Phase 6: suppression bitmask, LDS-broadcast row scheme ----
    // One row per thread; wave wv owns row-block perm{0,1,2,3,7,6,5,4}[wv] so
    // each SIMD's wave pair gets 9 j-blocks total. Broadcast reads of bj/aj
    // (wave-uniform address, conflict-free); branch-free fma sign test with a
    // per-block fmin-accumulated guard band; rare exact-div block fallback.
    {
        const int wv = tid >> 6;
        const int lane = tid & 63;
        const int rb = (wv < 4) ? wv : (11 - wv);
        const int i = rb * 64 + lane;
        const float4 bi = sm.sbox[i];       // sentinel if i >= N
        const float ai = sm.sarea[i];
        // triangular row base: block rb starts at 32*rb*(17-rb), stride (8-rb)
        const int rowBase = 32 * rb * (17 - rb) + lane * (8 - rb);
        const int nblk = (N + 63) >> 6;
        u64 anyb = 0ull;
        for (int jbk = rb; jbk < nblk; ++jbk) {
            const int j0 = jbk << 6;
            u64 bits = 0ull;
            float nearAcc = 1.0f;
            #pragma unroll 16
            for (int jj = 0; jj < 64; ++jj) {
                const float4 bj = sm.sbox[j0 + jj];     // broadcast
                const float aj = sm.sarea[j0 + jj];     // broadcast
                float xx1 = fmaxf(bj.x, bi.x);
                float yy1 = fmaxf(bj.y, bi.y);
                float xx2 = fminf(bj.z, bi.z);
                float yy2 = fminf(bj.w, bi.w);
                float iw = fmaxf(__fsub_rn(xx2, xx1), 0.0f);
                float ih = fmaxf(__fsub_rn(yy2, yy1), 0.0f);
                float inter = __fmul_rn(iw, ih);
                float denom = __fadd_rn(__fsub_rn(aj, inter), ai);   // ref order; > 0 always
                // sign(d) == sign(inter - 0.45*denom) exactly (single rounding)
                float d = __builtin_fmaf(-NMS_THR, denom, inter);
                // near iff |d| <= eps*denom  (inter==0 gives |d|=0.45*denom -> never near)
                nearAcc = fminf(nearAcc, __builtin_fmaf(-NEAR_EPS, denom, fabsf(d)));
                bits |= (d > 0.0f) ? (1ull << jj) : 0ull;
            }
            if (__builtin_expect(__any(nearAcc <= 0.0f), 0)) {
                // exact fallback: replicate reference fl(inter/denom) > 0.45f
                bits = 0ull;
                for (int jj = 0; jj < 64; ++jj) {
                    const float4 bj = sm.sbox[j0 + jj];
                    const float aj = sm.sarea[j0 + jj];
                    float xx1 = fmaxf(bj.x, bi.x);
                    float yy1 = fmaxf(bj.y, bi.y);
                    float xx2 = fminf(bj.z, bi.z);
                    float yy2 = fminf(bj.w, bi.w);
                    float iw = fmaxf(__fsub_rn(xx2, xx1), 0.0f);
                    float ih = fmaxf(__fsub_rn(yy2, yy1), 0.0f);
                    float inter = __fmul_rn(iw, ih);
                    float denom = __fadd_rn(__fsub_rn(aj, inter), ai);
                    bits |= (__fdiv_rn(inter, denom) > NMS_THR) ? (1ull << jj) : 0ull;
                }
            }
            if (jbk == rb) bits &= ~((2ull << lane) - 1ull);  // keep j > i only
            sm.u.tri[rowBase + (jbk - rb)] = bits;            // zeros for sentinel rows
            anyb |= bits;
        }
        u64 flag = __ballot(anyb != 0ull);
        if (lane == 0) sm.rowflag[rb] = flag;
    }
    __syncthreads();

    // ---- Phase 7: greedy sweep, single-wave lane-parallel ----
    // Lane l owns alive-word l. Stage w: word w's diagonal masks preloaded
    // per-lane (register-resident readlane chain, no LDS latency in the serial
    // chain); cross-word suppression of applied rows accumulated into per-lane
    // acc via one coalesced LDS read per row (off the dependency chain).
    if (tid < 64) {
        const int lane = tid;
        u64 cur = 0ull;
        if (lane < 8) {
            int lo = lane * 64;
            cur = (N >= lo + 64) ? ~0ull
                : (N <= lo)      ? 0ull
                : ((1ull << (N - lo)) - 1ull);
        }
        u64 acc = 0ull;   // lane l: union of forward masks hitting word l
        for (int w = 0; w < 8; ++w) {
            const int wb = 32 * w * (17 - w);
            const int ws = 8 - w;
            // diag word w of row 64w+lane (valid for all 64 lanes)
            u64 dm = sm.u.tri[wb + lane * ws];
            u64 f = sm.rowflag[w];
            if (f) {
                u64 curw = rl64(cur, w) & ~rl64(acc, w);
                while (f) {
                    int bpos = __ffsll((unsigned long long)f) - 1;
                    f &= f - 1;
                    if ((curw >> bpos) & 1ull) {
                        curw &= ~rl64(dm, bpos);                 // in-word, register-resident
                        u64 m = sm.u.tri[wb + bpos * ws + (lane - w)];
                        acc |= (lane > w && lane < 8) ? m : 0ull; // words w+1..7
                    }
                }
                cur = (lane == w) ? curw : cur;
            } else {
                // still need acc applied to word w even if no flags
                u64 curw = rl64(cur, w) & ~rl64(acc, w);
                cur = (lane == w) ? curw : cur;
            }
        }
        if (lane < 8) sm.alive[lane] = cur;
    }
    __syncthreads();
    if (tid == 0) {
        int pref = 0;
        #pragma unroll
        for (int w = 0; w < 8; ++w) {
            sm.wordpref[w] = pref;
            pref += __popcll(sm.alive[w]);
        }
        sm.n_emit = pref;
    }
    __syncthreads();
    if (tid < TOPK) {
        int w = tid >> 6, bpos = tid & 63;
        u64 aw = sm.alive[w];
        if ((aw >> bpos) & 1ull) {
            int pos = sm.wordpref[w] + __popcll(aw & ((1ull << bpos) - 1ull));
            sm.order[pos] = tid;
        }
    }
    __syncthreads();

    // ---- Phase 8: write full [500,5] slab (zeros beyond cnt) ----
    float* o = out + ((size_t)(b * NCLS + c)) * TOPK * 5;
    const int cnt = sm.n_emit;
    for (int f = tid; f < TOPK * 5; f += NTHREADS) {
        int k = f / 5;
        int r = f - k * 5;
        float val = 0.0f;
        if (k < cnt) {
            int i = sm.order[k];
            float4 bx = sm.sbox[i];
            val = (r == 0) ? sm.sscore[i]
                : (r == 1) ? bx.x
                : (r == 2) ? bx.y
                : (r == 3) ? bx.z
                :            bx.w;
        }
        o[f] = val;
    }
}

extern "C" void kernel_launch(void* const* d_in, const int* in_sizes, int n_in,
                              void* d_out, int out_size, void* d_ws, size_t ws_size,
                              hipStream_t stream) {
    const float* arm_loc  = (const float*)d_in[0];
    const float* arm_conf = (const float*)d_in[1];
    const float* odm_loc  = (const float*)d_in[2];
    const float* odm_conf = (const float*)d_in[3];
    const float* priors   = (const float*)d_in[4];
    float* out = (float*)d_out;

    const int grid = NTASK + B_NUM;   // 640 tasks + 32 class-0 zeroers
    const size_t need = (size_t)NTASK * P_NUM * sizeof(float); // 41.8 MB
    if (ws_size >= need) {
        float* wsf = (float*)d_ws;
        mask_transpose<<<B_NUM * 64, 256, 0, stream>>>(arm_conf, odm_conf, wsf);
        refinedet_main<true><<<grid, NTHREADS, 0, stream>>>(
            arm_loc, arm_conf, odm_loc, odm_conf, priors, wsf, out);
    } else {
        refinedet_main<false><<<grid, NTHREADS, 0, stream>>>(
            arm_loc, arm_conf, odm_loc, odm_conf, priors, nullptr, out);
    }
}

// Round 6
// 206.168 us; speedup vs baseline: 1.2994x; 1.0417x over previous
//
#include <hip/hip_runtime.h>
#include <math.h>

#define P_NUM   16320
#define B_NUM   32
#define NCLS    21
#define TOPK    500
#define CONF_THR 0.01f
#define NMS_THR  0.45f
#define OBJ_THR  0.01f
#define NBUCKET 2048
#define CAND_CAP 1024
#define NTHREADS 512
#define CHUNK   256
#define NTASK   (B_NUM * (NCLS - 1))
#define TRI_WORDS 2304       // sum_{b=0..7} 64*(8-b)
#define NEAR_EPS 1e-6f       // guard zone; fma-vs-div disagreement needs ~3e-8 rel

// per-task slab layout inside ws (65,280 B = 16320 floats), overlaying scores:
//   float ofs 0    : sbox  float4[512]   (8192 B)
//   float ofs 2048 : sarea float[512]    (2048 B)
//   float ofs 2560 : sscore float[512]   (2048 B)
//   float ofs 3072 : N (int)
//   float ofs 3088 : tri u64[2304]       (18432 B)  -> ends at float 7696 < 16320
#define SLAB_AREA  2048
#define SLAB_SCORE 2560
#define SLAB_N     3072
#define SLAB_TRI   3088

typedef unsigned long long u64;
typedef unsigned int u32;

struct SMemA {
    u32 hist[NBUCKET];    // 8192 B
    int csum[NTHREADS];   // 2048 B
    int gsum[64];         // 256 B
    u64 keys[CAND_CAP];   // 8192 B  (also cross-wave sort exchange buffer)
};

// monolithic-fallback shared block (kept verbatim from verified round-4 kernel)
struct SMem {
    union {
        SMemA a;            // phases 0-4
        u64 tri[TRI_WORDS]; // triangular mask (phases 6-7)
    } u;
    float4 sbox[512];
    float  sscore[512];
    float  sarea[512];
    int    order[512];
    u64    rowflag[8];
    u64    alive[8];
    int    wordpref[8];
    int    cand_count;
    int    bstar;
    int    n_emit;
};

// ---- mask + transpose odm_conf into per-task contiguous score arrays ----
__global__ __launch_bounds__(256)
void mask_transpose(const float* __restrict__ arm_conf,
                    const float* __restrict__ odm_conf,
                    float* __restrict__ ws) {
    __shared__ float tile[NCLS][CHUNK + 1];
    __shared__ float obj[CHUNK];
    const int blk = blockIdx.x;
    const int b = blk >> 6;
    const int ch = blk & 63;
    const int p0 = ch * CHUNK;
    const int np = min(CHUNK, P_NUM - p0);    // 256, last chunk 192
    const int tid = threadIdx.x;

    const float4* oc4 = (const float4*)(odm_conf + ((size_t)b * P_NUM + p0) * NCLS);
    const float* ac = arm_conf + ((size_t)b * P_NUM + p0) * 2;
    const int count4 = (np * NCLS) / 4;       // 1344 or 1008
    for (int q = tid; q < count4; q += 256) {
        float4 v = oc4[q];                    // coalesced 16B
        int f = 4 * q;
        { int p = f / NCLS;     int cc = f - p * NCLS;     tile[cc][p] = v.x; }
        { int p = (f+1) / NCLS; int cc = (f+1) - p * NCLS; tile[cc][p] = v.y; }
        { int p = (f+2) / NCLS; int cc = (f+2) - p * NCLS; tile[cc][p] = v.z; }
        { int p = (f+3) / NCLS; int cc = (f+3) - p * NCLS; tile[cc][p] = v.w; }
    }
    if (tid < np) obj[tid] = ac[tid * 2 + 1];
    __syncthreads();

    const int nv = np / 4;                    // 64 or 48
    const int total = 20 * nv;
    for (int i = tid; i < total; i += 256) {
        int cc = i / nv;                      // 0..19 -> class cc+1
        int pp = i - cc * nv;
        const float* t = &tile[cc + 1][4 * pp];
        float4 ov = make_float4(
            (obj[4*pp+0] > OBJ_THR) ? t[0] : 0.0f,
            (obj[4*pp+1] > OBJ_THR) ? t[1] : 0.0f,
            (obj[4*pp+2] > OBJ_THR) ? t[2] : 0.0f,
            (obj[4*pp+3] > OBJ_THR) ? t[3] : 0.0f);
        float4* w4 = (float4*)(ws + ((size_t)(b * 20 + cc)) * P_NUM + p0);
        w4[pp] = ov;                          // coalesced 16B store
    }
}

// 64-bit readlane (lane index wave-uniform)
__device__ __forceinline__ u64 rl64(u64 x, int l) {
    u32 lo = (u32)__builtin_amdgcn_readlane((int)(u32)x, l);
    u32 hi = (u32)__builtin_amdgcn_readlane((int)(u32)(x >> 32), l);
    return ((u64)hi << 32) | lo;
}

// ---- decode helper (exact ref FP sequence) ----
__device__ __forceinline__ void decode_box(const float* __restrict__ arm_loc,
                                           const float* __restrict__ odm_loc,
                                           const float* __restrict__ priors,
                                           int b, int p,
                                           float4& box, float& area) {
    float4 pr = ((const float4*)priors)[p];
    float4 al = ((const float4*)(arm_loc + (size_t)b * P_NUM * 4))[p];
    float4 ol = ((const float4*)(odm_loc + (size_t)b * P_NUM * 4))[p];
    float cx = __fadd_rn(pr.x, __fmul_rn(__fmul_rn(al.x, 0.1f), pr.z));
    float cy = __fadd_rn(pr.y, __fmul_rn(__fmul_rn(al.y, 0.1f), pr.w));
    float w  = __fmul_rn(pr.z, (float)exp((double)__fmul_rn(al.z, 0.2f)));
    float h  = __fmul_rn(pr.w, (float)exp((double)__fmul_rn(al.w, 0.2f)));
    float mnx = __fsub_rn(cx, __fmul_rn(w, 0.5f));
    float mny = __fsub_rn(cy, __fmul_rn(h, 0.5f));
    float mxx = __fadd_rn(mnx, w);
    float mxy = __fadd_rn(mny, h);
    float dcx = __fmul_rn(__fadd_rn(mxx, mnx), 0.5f);
    float dcy = __fmul_rn(__fadd_rn(mxy, mny), 0.5f);
    float dw  = __fsub_rn(mxx, mnx);
    float dh  = __fsub_rn(mxy, mny);
    float cx2 = __fadd_rn(dcx, __fmul_rn(__fmul_rn(ol.x, 0.1f), dw));
    float cy2 = __fadd_rn(dcy, __fmul_rn(__fmul_rn(ol.y, 0.1f), dh));
    float w2  = __fmul_rn(dw, (float)exp((double)__fmul_rn(ol.z, 0.2f)));
    float h2  = __fmul_rn(dh, (float)exp((double)__fmul_rn(ol.w, 0.2f)));
    float x1 = __fsub_rn(cx2, __fmul_rn(w2, 0.5f));
    float y1 = __fsub_rn(cy2, __fmul_rn(h2, 0.5f));
    float x2 = __fadd_rn(x1, w2);
    float y2 = __fadd_rn(y1, h2);
    box = make_float4(x1, y1, x2, y2);
    area = __fmul_rn(__fsub_rn(x2, x1), __fsub_rn(y2, y1));
}

// =====================  kernel A: select + sort + decode  =====================
__global__ __launch_bounds__(NTHREADS)
void rdet_select(const float* __restrict__ arm_loc,
                 const float* __restrict__ odm_loc,
                 const float* __restrict__ priors,
                 float* __restrict__ ws) {
    __shared__ SMemA sa;
    __shared__ int s_count, s_bstar;
    const int task = blockIdx.x;
    const int tid = threadIdx.x;
    const int b = task / (NCLS - 1);
    float* slab = ws + (size_t)task * P_NUM;

    // ---- Phase 0: load my 32 scores into registers ----
    float s[32];
    {
        const float4* sp = (const float4*)slab;
        #pragma unroll
        for (int v = 0; v < 8; ++v) {
            int q = tid + 512 * v;            // 4080 float4s total
            float4 val = (q < 4080) ? sp[q] : make_float4(0.f, 0.f, 0.f, 0.f);
            s[4 * v + 0] = val.x; s[4 * v + 1] = val.y;
            s[4 * v + 2] = val.z; s[4 * v + 3] = val.w;
        }
    }
    for (int i = tid; i < NBUCKET; i += NTHREADS) sa.hist[i] = 0u;
    if (tid == 0) s_count = 0;
    __syncthreads();

    // ---- Phase 1: histogram ----
    #pragma unroll 4
    for (int k = 0; k < 32; ++k) {
        float sc = s[k];
        if (sc > CONF_THR) {
            int bk = (int)(sc * (float)NBUCKET);
            if (bk > NBUCKET - 1) bk = NBUCKET - 1;
            atomicAdd(&sa.hist[bk], 1u);
        }
    }
    __syncthreads();

    // ---- Phase 2: threshold bucket ----
    {
        int s4 = 0;
        #pragma unroll
        for (int q = 0; q < 4; ++q) s4 += (int)sa.hist[tid * 4 + q];
        sa.csum[tid] = s4;
    }
    __syncthreads();
    if (tid < 64) {
        int g = 0;
        #pragma unroll
        for (int q = 0; q < 8; ++q) g += sa.csum[tid * 8 + q];
        sa.gsum[tid] = g;
    }
    __syncthreads();
    if (tid == 0) {
        int cum = 0, bstar = 0;
        for (int gg = 63; gg >= 0; --gg) {
            int gs = sa.gsum[gg];
            if (cum + gs >= TOPK) {
                for (int t = gg * 8 + 7; t >= gg * 8; --t) {
                    int cs = sa.csum[t];
                    if (cum + cs >= TOPK) {
                        for (int bk = t * 4 + 3; bk >= t * 4; --bk) {
                            cum += (int)sa.hist[bk];
                            if (cum >= TOPK) { bstar = bk; goto found; }
                        }
                    }
                    cum += cs;
                }
            }
            cum += gs;
        }
found:
        s_bstar = bstar;
    }
    __syncthreads();
    const int bstar = s_bstar;

    // ---- Phase 3: gather candidates ----
    #pragma unroll 4
    for (int k = 0; k < 32; ++k) {
        float sc = s[k];
        if (sc > CONF_THR) {
            int bk = (int)(sc * (float)NBUCKET);
            if (bk > NBUCKET - 1) bk = NBUCKET - 1;
            if (bk >= bstar) {
                int p = 4 * (tid + 512 * (k >> 2)) + (k & 3);   // PACKED layout
                int pos = atomicAdd(&s_count, 1);
                if (pos < CAND_CAP) {
                    u64 key = ((u64)__float_as_uint(sc) << 32) | (u32)(~(u32)p);
                    sa.keys[pos] = key;
                }
            }
        }
    }
    __syncthreads();
    int M = s_count; if (M > CAND_CAP) M = CAND_CAP;

    // ---- Phase 4: sort descending ----
    u64 v;
    if (__builtin_expect(M <= 512, 1)) {
        for (int i = M + tid; i < 512; i += NTHREADS) sa.keys[i] = 0ull;
        __syncthreads();
        v = sa.keys[tid];
        #pragma unroll
        for (int k = 2; k <= 512; k <<= 1) {
            for (int j = k >> 1; j > 0; j >>= 1) {
                u64 p;
                if (j >= 64) {
                    sa.keys[tid] = v;
                    __syncthreads();
                    p = sa.keys[tid ^ j];
                    __syncthreads();
                } else {
                    p = __shfl_xor((unsigned long long)v, j, 64);
                }
                const bool desc = ((tid & k) == 0);
                const bool lower = ((tid & j) == 0);
                const bool takeMax = (desc == lower);
                v = (takeMax == (v < p)) ? p : v;
            }
        }
    } else {
        for (int i = M + tid; i < CAND_CAP; i += NTHREADS) sa.keys[i] = 0ull;
        __syncthreads();
        for (int k = 2; k <= CAND_CAP; k <<= 1) {
            for (int j = k >> 1; j > 0; j >>= 1) {
                for (int t = tid; t < CAND_CAP; t += NTHREADS) {
                    int ixj = t ^ j;
                    if (ixj > t) {
                        u64 a = sa.keys[t];
                        u64 bb = sa.keys[ixj];
                        bool desc = ((t & k) == 0);
                        if (desc ? (a < bb) : (a > bb)) {
                            sa.keys[t] = bb;
                            sa.keys[ixj] = a;
                        }
                    }
                }
                __syncthreads();
            }
        }
        v = sa.keys[tid];
    }
    const int N = (M < TOPK) ? M : TOPK;

    // ---- Phase 5: decode + write slab (overlays consumed scores) ----
    float4 box; float area, score;
    if (tid < N) {
        score = __uint_as_float((u32)(v >> 32));
        int p = (int)(~(u32)(v & 0xFFFFFFFFull));
        decode_box(arm_loc, odm_loc, priors, b, p, box, area);
    } else {
        box = make_float4(2.0f, 2.0f, -2.0f, -2.0f);  // inter==0 vs anything; area>0
        area = 16.0f;
        score = 0.0f;
    }
    ((float4*)slab)[tid] = box;
    slab[SLAB_AREA + tid] = area;
    slab[SLAB_SCORE + tid] = score;
    if (tid == 0) ((int*)slab)[SLAB_N] = N;
}

// =====================  kernel B: IoU suppression-mask tiles  =====================
struct BMem {
    float4 sbox[512];     // 8192 B
    float  sarea[512];    // 2048 B
    int    sN;
};

__global__ __launch_bounds__(256)
void rdet_masks(float* __restrict__ ws) {
    __shared__ BMem bm;
    const int task = blockIdx.x / 9;
    const int tg   = blockIdx.x % 9;
    const int tid = threadIdx.x;
    float* slab = ws + (size_t)task * P_NUM;

    // stage sbox + sarea (640 contiguous float4)
    {
        const float4* src = (const float4*)slab;
        for (int q = tid; q < 640; q += 256) {
            float4 vv = src[q];
            if (q < 512) bm.sbox[q] = vv;
            else ((float4*)bm.sarea)[q - 512] = vv;
        }
        if (tid == 0) bm.sN = ((const int*)slab)[SLAB_N];
    }
    __syncthreads();
    const int N = bm.sN;
    const int nblk = (N + 63) >> 6;
    const int wv = tid >> 6;
    const int lane = tid & 63;

    // tile index 0..35 -> (rb, jb) upper-triangular, rb-major.
    // NOTE: advance must be guarded by rb==r so it cannot re-trigger after the
    // first failure (unguarded version mis-mapped e.g. t=13 -> (2,2) instead of
    // (1,6), leaving tiles unwritten -- the round-5 correctness bug).
    const int t = tg * 4 + wv;
    int rb = 0, base = 0;
    #pragma unroll
    for (int r = 0; r < 7; ++r) {
        int cnt = 8 - r;
        if (rb == r && t >= base + cnt) { base += cnt; rb = r + 1; }
    }
    const int jb = rb + (t - base);
    if (jb >= nblk) return;                   // whole wave exits (no barrier below)

    const int i = rb * 64 + lane;
    const float4 bi = bm.sbox[i];
    const float ai = bm.sarea[i];
    const int j0 = jb << 6;

    u64 bits = 0ull;
    float nearAcc = 1.0f;
    #pragma unroll 16
    for (int jj = 0; jj < 64; ++jj) {
        const float4 bj = bm.sbox[j0 + jj];     // broadcast
        const float aj = bm.sarea[j0 + jj];     // broadcast
        float xx1 = fmaxf(bj.x, bi.x);
        float yy1 = fmaxf(bj.y, bi.y);
        float xx2 = fminf(bj.z, bi.z);
        float yy2 = fminf(bj.w, bi.w);
        float iw = fmaxf(__fsub_rn(xx2, xx1), 0.0f);
        float ih = fmaxf(__fsub_rn(yy2, yy1), 0.0f);
        float inter = __fmul_rn(iw, ih);
        float denom = __fadd_rn(__fsub_rn(aj, inter), ai);   // ref order; > 0 always
        float d = __builtin_fmaf(-NMS_THR, denom, inter);    // sign-exact vs inter-0.45*denom
        nearAcc = fminf(nearAcc, __builtin_fmaf(-NEAR_EPS, denom, fabsf(d)));
        bits |= (d > 0.0f) ? (1ull << jj) : 0ull;
    }
    if (__builtin_expect(__any(nearAcc <= 0.0f), 0)) {
        // exact fallback: replicate reference fl(inter/denom) > 0.45f
        bits = 0ull;
        for (int jj = 0; jj < 64; ++jj) {
            const float4 bj = bm.sbox[j0 + jj];
            const float aj = bm.sarea[j0 + jj];
            float xx1 = fmaxf(bj.x, bi.x);
            float yy1 = fmaxf(bj.y, bi.y);
            float xx2 = fminf(bj.z, bi.z);
            float yy2 = fminf(bj.w, bi.w);
            float iw = fmaxf(__fsub_rn(xx2, xx1), 0.0f);
            float ih = fmaxf(__fsub_rn(yy2, yy1), 0.0f);
            float inter = __fmul_rn(iw, ih);
            float denom = __fadd_rn(__fsub_rn(aj, inter), ai);
            bits |= (__fdiv_rn(inter, denom) > NMS_THR) ? (1ull << jj) : 0ull;
        }
    }
    if (jb == rb) bits &= ~((2ull << lane) - 1ull);  // keep j > i only
    u64* tri = (u64*)(slab + SLAB_TRI);
    tri[32 * rb * (17 - rb) + lane * (8 - rb) + (jb - rb)] = bits;
}

// =====================  kernel C: greedy sweep + output  =====================
struct CMem {
    u64    tri[TRI_WORDS];   // FIRST: sweep's masked-out lanes may read up to ~55 words past
    float4 sbox[512];        //        the end; sbox follows so the read stays in-block.
    float  sscore[512];
    int    order[512];
    u64    rowflag[8];
    u64    alive[8];
    int    wordpref[8];
    int    n_emit;
    int    sN;
};

__global__ __launch_bounds__(NTHREADS)
void rdet_nms_out(const float* __restrict__ ws, float* __restrict__ out) {
    __shared__ CMem cm;
    const int task = blockIdx.x;
    const int tid = threadIdx.x;

    if (task >= NTASK) {                      // class-0 slab zeroers
        float* o = out + (size_t)(task - NTASK) * NCLS * TOPK * 5;
        for (int f = tid; f < TOPK * 5; f += NTHREADS) o[f] = 0.0f;
        return;
    }
    const int b = task / (NCLS - 1);
    const int c = task % (NCLS - 1) + 1;
    const float* slab = ws + (size_t)task * P_NUM;

    // stage sbox (f4 0..511), sscore (f4 640..767), tri (f4 772..1923)
    {
        const float4* src = (const float4*)slab;
        for (int q = tid; q < 512; q += NTHREADS) cm.sbox[q] = src[q];
        if (tid < 128) ((float4*)cm.sscore)[tid] = src[640 + tid];
        for (int q = tid; q < 1152; q += NTHREADS) ((float4*)cm.tri)[q] = src[772 + q];
        if (tid == 0) cm.sN = ((const int*)slab)[SLAB_N];
    }
    __syncthreads();
    const int N = cm.sN;
    const int nblk = (N + 63) >> 6;

    // rowflag: one thread per row ORs its row's COMPUTED words only
    // (words >= nblk hold stale workspace data; excluding them keeps rowflag
    // exact, though spurious flags would be benign: such rows' computed diag
    // words are zero and cur=0 masks words >= nblk.)
    {
        int rb = tid >> 6, ln = tid & 63;
        int wstep = 8 - rb;
        int base = 32 * rb * (17 - rb) + ln * wstep;
        int kmax = nblk - rb;                 // computed words for this row block
        u64 o = 0ull;
        for (int k = 0; k < wstep; ++k)
            o |= (k < kmax) ? cm.tri[base + k] : 0ull;
        u64 flag = __ballot(o != 0ull);       // wave == one rb group
        if (ln == 0) cm.rowflag[rb] = flag;
    }
    __syncthreads();

    // greedy sweep, single-wave lane-parallel (lane l owns alive-word l)
    if (tid < 64) {
        const int lane = tid;
        u64 cur = 0ull;
        if (lane < 8) {
            int lo = lane * 64;
            cur = (N >= lo + 64) ? ~0ull
                : (N <= lo)      ? 0ull
                : ((1ull << (N - lo)) - 1ull);
        }
        u64 acc = 0ull;
        for (int w = 0; w < 8; ++w) {
            const int wb = 32 * w * (17 - w);
            const int wstep = 8 - w;
            u64 dm = cm.tri[wb + lane * wstep];       // diag word of row 64w+lane
            u64 f = cm.rowflag[w];
            u64 curw = rl64(cur, w) & ~rl64(acc, w);
            while (f) {
                int bpos = __ffsll((unsigned long long)f) - 1;
                f &= f - 1;
                if ((curw >> bpos) & 1ull) {
                    curw &= ~rl64(dm, bpos);          // in-word, register-resident
                    u64 m = cm.tri[wb + bpos * wstep + (lane - w)];
                    acc |= (lane > w && lane < 8) ? m : 0ull;
                }
            }
            cur = (lane == w) ? curw : cur;
        }
        if (lane < 8) cm.alive[lane] = cur;
    }
    __syncthreads();
    if (tid == 0) {
        int pref = 0;
        #pragma unroll
        for (int w = 0; w < 8; ++w) {
            cm.wordpref[w] = pref;
            pref += __popcll(cm.alive[w]);
        }
        cm.n_emit = pref;
    }
    __syncthreads();
    if (tid < TOPK) {
        int w = tid >> 6, bpos = tid & 63;
        u64 aw = cm.alive[w];
        if ((aw >> bpos) & 1ull) {
            int pos = cm.wordpref[w] + __popcll(aw & ((1ull << bpos) - 1ull));
            cm.order[pos] = tid;
        }
    }
    __syncthreads();

    float* o = out + ((size_t)(b * NCLS + c)) * TOPK * 5;
    const int cnt = cm.n_emit;
    for (int f = tid; f < TOPK * 5; f += NTHREADS) {
        int k = f / 5;
        int r = f - k * 5;
        float val = 0.0f;
        if (k < cnt) {
            int i = cm.order[k];
            float4 bx = cm.sbox[i];
            val = (r == 0) ? cm.sscore[i]
                : (r == 1) ? bx.x
                : (r == 2) ? bx.y
                : (r == 3) ? bx.z
                :            bx.w;
        }
        o[f] = val;
    }
}

// =====================  monolithic fallback (no workspace), round-4 verified  =====================
__global__ __launch_bounds__(NTHREADS)
void refinedet_mono(const float* __restrict__ arm_loc,
                    const float* __restrict__ arm_conf,
                    const float* __restrict__ odm_loc,
                    const float* __restrict__ odm_conf,
                    const float* __restrict__ priors,
                    float* __restrict__ out) {
    __shared__ SMem sm;
    const int task = blockIdx.x;
    const int tid = threadIdx.x;

    if (task >= NTASK) {
        float* o = out + (size_t)(task - NTASK) * NCLS * TOPK * 5;
        for (int f = tid; f < TOPK * 5; f += NTHREADS) o[f] = 0.0f;
        return;
    }

    const int b = task / (NCLS - 1);
    const int c = task % (NCLS - 1) + 1;

    float s[32];
    {
        const float* armc = arm_conf + (size_t)b * P_NUM * 2;
        const float* odmc = odm_conf + (size_t)b * P_NUM * NCLS;
        #pragma unroll 4
        for (int k = 0; k < 32; ++k) {
            int p = tid + 512 * k;
            float sc = 0.0f;
            if (p < P_NUM) {
                float o = armc[p * 2 + 1];
                sc = (o > OBJ_THR) ? odmc[p * NCLS + c] : 0.0f;
            }
            s[k] = sc;
        }
    }
    for (int i = tid; i < NBUCKET; i += NTHREADS) sm.u.a.hist[i] = 0u;
    if (tid == 0) sm.cand_count = 0;
    __syncthreads();

    #pragma unroll 4
    for (int k = 0; k < 32; ++k) {
        float sc = s[k];
        if (sc > CONF_THR) {
            int bk = (int)(sc * (float)NBUCKET);
            if (bk > NBUCKET - 1) bk = NBUCKET - 1;
            atomicAdd(&sm.u.a.hist[bk], 1u);
        }
    }
    __syncthreads();
    {
        int s4 = 0;
        #pragma unroll
        for (int q = 0; q < 4; ++q) s4 += (int)sm.u.a.hist[tid * 4 + q];
        sm.u.a.csum[tid] = s4;
    }
    __syncthreads();
    if (tid < 64) {
        int g = 0;
        #pragma unroll
        for (int q = 0; q < 8; ++q) g += sm.u.a.csum[tid * 8 + q];
        sm.u.a.gsum[tid] = g;
    }
    __syncthreads();
    if (tid == 0) {
        int cum = 0, bstar = 0;
        for (int gg = 63; gg >= 0; --gg) {
            int gs = sm.u.a.gsum[gg];
            if (cum + gs >= TOPK) {
                for (int t = gg * 8 + 7; t >= gg * 8; --t) {
                    int cs = sm.u.a.csum[t];
                    if (cum + cs >= TOPK) {
                        for (int bk = t * 4 + 3; bk >= t * 4; --bk) {
                            cum += (int)sm.u.a.hist[bk];
                            if (cum >= TOPK) { bstar = bk; goto foundm; }
                        }
                    }
                    cum += cs;
                }
            }
            cum += gs;
        }
foundm:
        sm.bstar = bstar;
    }
    __syncthreads();
    const int bstar = sm.bstar;

    #pragma unroll 4
    for (int k = 0; k < 32; ++k) {
        float sc = s[k];
        if (sc > CONF_THR) {
            int bk = (int)(sc * (float)NBUCKET);
            if (bk > NBUCKET - 1) bk = NBUCKET - 1;
            if (bk >= bstar) {
                int p = tid + 512 * k;
                int pos = atomicAdd(&sm.cand_count, 1);
                if (pos < CAND_CAP) {
                    u64 key = ((u64)__float_as_uint(sc) << 32) | (u32)(~(u32)p);
                    sm.u.a.keys[pos] = key;
                }
            }
        }
    }
    __syncthreads();
    int M = sm.cand_count; if (M > CAND_CAP) M = CAND_CAP;

    u64 v;
    if (__builtin_expect(M <= 512, 1)) {
        for (int i = M + tid; i < 512; i += NTHREADS) sm.u.a.keys[i] = 0ull;
        __syncthreads();
        v = sm.u.a.keys[tid];
        #pragma unroll
        for (int k = 2; k <= 512; k <<= 1) {
            for (int j = k >> 1; j > 0; j >>= 1) {
                u64 p;
                if (j >= 64) {
                    sm.u.a.keys[tid] = v;
                    __syncthreads();
                    p = sm.u.a.keys[tid ^ j];
                    __syncthreads();
                } else {
                    p = __shfl_xor((unsigned long long)v, j, 64);
                }
                const bool desc = ((tid & k) == 0);
                const bool lower = ((tid & j) == 0);
                const bool takeMax = (desc == lower);
                v = (takeMax == (v < p)) ? p : v;
            }
        }
    } else {
        for (int i = M + tid; i < CAND_CAP; i += NTHREADS) sm.u.a.keys[i] = 0ull;
        __syncthreads();
        for (int k = 2; k <= CAND_CAP; k <<= 1) {
            for (int j = k >> 1; j > 0; j >>= 1) {
                for (int t = tid; t < CAND_CAP; t += NTHREADS) {
                    int ixj = t ^ j;
                    if (ixj > t) {
                        u64 a = sm.u.a.keys[t];
                        u64 bb = sm.u.a.keys[ixj];
                        bool desc = ((t & k) == 0);
                        if (desc ? (a < bb) : (a > bb)) {
                            sm.u.a.keys[t] = bb;
                            sm.u.a.keys[ixj] = a;
                        }
                    }
                }
                __syncthreads();
            }
        }
        v = sm.u.a.keys[tid];
    }
    const int N = (M < TOPK) ? M : TOPK;

    if (tid < 8) sm.rowflag[tid] = 0ull;
    if (tid < N) {
        float sc = __uint_as_float((u32)(v >> 32));
        int p = (int)(~(u32)(v & 0xFFFFFFFFull));
        float4 box; float area;
        decode_box(arm_loc, odm_loc, priors, b, p, box, area);
        sm.sbox[tid] = box;
        sm.sscore[tid] = sc;
        sm.sarea[tid] = area;
    } else {
        sm.sbox[tid] = make_float4(2.0f, 2.0f, -2.0f, -2.0f);
        sm.sscore[tid] = 0.0f;
        sm.sarea[tid] = 16.0f;
    }
    __syncthreads();

    {
        const int wv = tid >> 6;
        const int lane = tid & 63;
        const int rb = (wv < 4) ? wv : (11 - wv);
        const int i = rb * 64 + lane;
        const float4 bi = sm.sbox[i];
        const float ai = sm.sarea[i];
        const int rowBase = 32 * rb * (17 - rb) + lane * (8 - rb);
        const int nblk = (N + 63) >> 6;
        u64 anyb = 0ull;
        for (int jbk = rb; jbk < nblk; ++jbk) {
            const int j0 = jbk << 6;
            u64 bits = 0ull;
            float nearAcc = 1.0f;
            #pragma unroll 16
            for (int jj = 0; jj < 64; ++jj) {
                const float4 bj = sm.sbox[j0 + jj];
                const float aj = sm.sarea[j0 + jj];
                float xx1 = fmaxf(bj.x, bi.x);
                float yy1 = fmaxf(bj.y, bi.y);
                float xx2 = fminf(bj.z, bi.z);
                float yy2 = fminf(bj.w, bi.w);
                float iw = fmaxf(__fsub_rn(xx2, xx1), 0.0f);
                float ih = fmaxf(__fsub_rn(yy2, yy1), 0.0f);
                float inter = __fmul_rn(iw, ih);
                float denom = __fadd_rn(__fsub_rn(aj, inter), ai);
                float d = __builtin_fmaf(-NMS_THR, denom, inter);
                nearAcc = fminf(nearAcc, __builtin_fmaf(-NEAR_EPS, denom, fabsf(d)));
                bits |= (d > 0.0f) ? (1ull << jj) : 0ull;
            }
            if (__builtin_expect(__any(nearAcc <= 0.0f), 0)) {
                bits = 0ull;
                for (int jj = 0; jj < 64; ++jj) {
                    const float4 bj = sm.sbox[j0 + jj];
                    const float aj = sm.sarea[j0 + jj];
                    float xx1 = fmaxf(bj.x, bi.x);
                    float yy1 = fmaxf(bj.y, bi.y);
                    float xx2 = fminf(bj.z, bi.z);
                    float yy2 = fminf(bj.w, bi.w);
                    float iw = fmaxf(__fsub_rn(xx2, xx1), 0.0f);
                    float ih = fmaxf(__fsub_rn(yy2, yy1), 0.0f);
                    float inter = __fmul_rn(iw, ih);
                    float denom = __fadd_rn(__fsub_rn(aj, inter), ai);
                    bits |= (__fdiv_rn(inter, denom) > NMS_THR) ? (1ull << jj) : 0ull;
                }
            }
            if (jbk == rb) bits &= ~((2ull << lane) - 1ull);
            sm.u.tri[rowBase + (jbk - rb)] = bits;
            anyb |= bits;
        }
        u64 flag = __ballot(anyb != 0ull);
        if (lane == 0) sm.rowflag[rb] = flag;
    }
    __syncthreads();

    if (tid < 64) {
        const int lane = tid;
        u64 cur = 0ull;
        if (lane < 8) {
            int lo = lane * 64;
            cur = (N >= lo + 64) ? ~0ull
                : (N <= lo)      ? 0ull
                : ((1ull << (N - lo)) - 1ull);
        }
        u64 acc = 0ull;
        for (int w = 0; w < 8; ++w) {
            const int wb = 32 * w * (17 - w);
            const int wstep = 8 - w;
            u64 dm = sm.u.tri[wb + lane * wstep];
            u64 f = sm.rowflag[w];
            u64 curw = rl64(cur, w) & ~rl64(acc, w);
            while (f) {
                int bpos = __ffsll((unsigned long long)f) - 1;
                f &= f - 1;
                if ((curw >> bpos) & 1ull) {
                    curw &= ~rl64(dm, bpos);
                    u64 m = sm.u.tri[wb + bpos * wstep + (lane - w)];
                    acc |= (lane > w && lane < 8) ? m : 0ull;
                }
            }
            cur = (lane == w) ? curw : cur;
        }
        if (lane < 8) sm.alive[lane] = cur;
    }
    __syncthreads();
    if (tid == 0) {
        int pref = 0;
        #pragma unroll
        for (int w = 0; w < 8; ++w) {
            sm.wordpref[w] = pref;
            pref += __popcll(sm.alive[w]);
        }
        sm.n_emit = pref;
    }
    __syncthreads();
    if (tid < TOPK) {
        int w = tid >> 6, bpos = tid & 63;
        u64 aw = sm.alive[w];
        if ((aw >> bpos) & 1ull) {
            int pos = sm.wordpref[w] + __popcll(aw & ((1ull << bpos) - 1ull));
            sm.order[pos] = tid;
        }
    }
    __syncthreads();

    float* o = out + ((size_t)(b * NCLS + c)) * TOPK * 5;
    const int cnt = sm.n_emit;
    for (int f = tid; f < TOPK * 5; f += NTHREADS) {
        int k = f / 5;
        int r = f - k * 5;
        float val = 0.0f;
        if (k < cnt) {
            int i = sm.order[k];
            float4 bx = sm.sbox[i];
            val = (r == 0) ? sm.sscore[i]
                : (r == 1) ? bx.x
                : (r == 2) ? bx.y
                : (r == 3) ? bx.z
                :            bx.w;
        }
        o[f] = val;
    }
}

extern "C" void kernel_launch(void* const* d_in, const int* in_sizes, int n_in,
                              void* d_out, int out_size, void* d_ws, size_t ws_size,
                              hipStream_t stream) {
    const float* arm_loc  = (const float*)d_in[0];
    const float* arm_conf = (const float*)d_in[1];
    const float* odm_loc  = (const float*)d_in[2];
    const float* odm_conf = (const float*)d_in[3];
    const float* priors   = (const float*)d_in[4];
    float* out = (float*)d_out;

    const size_t need = (size_t)NTASK * P_NUM * sizeof(float); // 41.8 MB
    if (ws_size >= need) {
        float* wsf = (float*)d_ws;
        mask_transpose<<<B_NUM * 64, 256, 0, stream>>>(arm_conf, odm_conf, wsf);
        rdet_select<<<NTASK, NTHREADS, 0, stream>>>(arm_loc, odm_loc, priors, wsf);
        rdet_masks<<<NTASK * 9, 256, 0, stream>>>(wsf);
        rdet_nms_out<<<NTASK + B_NUM, NTHREADS, 0, stream>>>(wsf, out);
    } else {
        refinedet_mono<<<NTASK + B_NUM, NTHREADS, 0, stream>>>(
            arm_loc, arm_conf, odm_loc, odm_conf, priors, out);
    }
}

// Round 7
// 203.955 us; speedup vs baseline: 1.3135x; 1.0109x over previous
//
#include <hip/hip_runtime.h>
#include <math.h>

#define P_NUM   16320
#define B_NUM   32
#define NCLS    21
#define TOPK    500
#define CONF_THR 0.01f
#define NMS_THR  0.45f
#define OBJ_THR  0.01f
#define NBUCKET 2048
#define CAND_CAP 1024
#define NTHREADS 512
#define CHUNK   256
#define NTASK   (B_NUM * (NCLS - 1))
#define TRI_WORDS 2304       // sum_{b=0..7} 64*(8-b)
#define NEAR_EPS 1e-6f       // guard zone; fma-vs-div disagreement needs ~3e-8 rel

// per-task slab layout inside ws (65,280 B = 16320 floats), overlaying scores:
//   float ofs 0    : sbox  float4[512]   (8192 B)
//   float ofs 2048 : sarea float[512]    (2048 B)
//   float ofs 2560 : sscore float[512]   (2048 B)
//   float ofs 3072 : N (int)
//   float ofs 3088 : tri u64[2304]       (18432 B)  -> ends at float 7696 < 16320
#define SLAB_AREA  2048
#define SLAB_SCORE 2560
#define SLAB_N     3072
#define SLAB_TRI   3088

typedef unsigned long long u64;
typedef unsigned int u32;

struct SMemA {
    u32 hist[NBUCKET];    // 8192 B
    int csum[NTHREADS];   // 2048 B
    int gsum[64];         // 256 B
    u64 keys[CAND_CAP];   // 8192 B  (also cross-wave sort exchange buffer)
};

// monolithic-fallback shared block (kept verbatim from verified round-4 kernel)
struct SMem {
    union {
        SMemA a;            // phases 0-4
        u64 tri[TRI_WORDS]; // triangular mask (phases 6-7)
    } u;
    float4 sbox[512];
    float  sscore[512];
    float  sarea[512];
    int    order[512];
    u64    rowflag[8];
    u64    alive[8];
    int    wordpref[8];
    int    cand_count;
    int    bstar;
    int    n_emit;
};

// ---- mask + transpose odm_conf into per-task contiguous score arrays ----
__global__ __launch_bounds__(256)
void mask_transpose(const float* __restrict__ arm_conf,
                    const float* __restrict__ odm_conf,
                    float* __restrict__ ws) {
    __shared__ float tile[NCLS][CHUNK + 1];
    __shared__ float obj[CHUNK];
    const int blk = blockIdx.x;
    const int b = blk >> 6;
    const int ch = blk & 63;
    const int p0 = ch * CHUNK;
    const int np = min(CHUNK, P_NUM - p0);    // 256, last chunk 192
    const int tid = threadIdx.x;

    const float4* oc4 = (const float4*)(odm_conf + ((size_t)b * P_NUM + p0) * NCLS);
    const float* ac = arm_conf + ((size_t)b * P_NUM + p0) * 2;
    const int count4 = (np * NCLS) / 4;       // 1344 or 1008
    for (int q = tid; q < count4; q += 256) {
        float4 v = oc4[q];                    // coalesced 16B
        int f = 4 * q;
        { int p = f / NCLS;     int cc = f - p * NCLS;     tile[cc][p] = v.x; }
        { int p = (f+1) / NCLS; int cc = (f+1) - p * NCLS; tile[cc][p] = v.y; }
        { int p = (f+2) / NCLS; int cc = (f+2) - p * NCLS; tile[cc][p] = v.z; }
        { int p = (f+3) / NCLS; int cc = (f+3) - p * NCLS; tile[cc][p] = v.w; }
    }
    if (tid < np) obj[tid] = ac[tid * 2 + 1];
    __syncthreads();

    const int nv = np / 4;                    // 64 or 48
    const int total = 20 * nv;
    for (int i = tid; i < total; i += 256) {
        int cc = i / nv;                      // 0..19 -> class cc+1
        int pp = i - cc * nv;
        const float* t = &tile[cc + 1][4 * pp];
        float4 ov = make_float4(
            (obj[4*pp+0] > OBJ_THR) ? t[0] : 0.0f,
            (obj[4*pp+1] > OBJ_THR) ? t[1] : 0.0f,
            (obj[4*pp+2] > OBJ_THR) ? t[2] : 0.0f,
            (obj[4*pp+3] > OBJ_THR) ? t[3] : 0.0f);
        float4* w4 = (float4*)(ws + ((size_t)(b * 20 + cc)) * P_NUM + p0);
        w4[pp] = ov;                          // coalesced 16B store
    }
}

// 64-bit readlane (lane index wave-uniform)
__device__ __forceinline__ u64 rl64(u64 x, int l) {
    u32 lo = (u32)__builtin_amdgcn_readlane((int)(u32)x, l);
    u32 hi = (u32)__builtin_amdgcn_readlane((int)(u32)(x >> 32), l);
    return ((u64)hi << 32) | lo;
}

// ---- decode helper (exact ref FP sequence) ----
__device__ __forceinline__ void decode_box(const float* __restrict__ arm_loc,
                                           const float* __restrict__ odm_loc,
                                           const float* __restrict__ priors,
                                           int b, int p,
                                           float4& box, float& area) {
    float4 pr = ((const float4*)priors)[p];
    float4 al = ((const float4*)(arm_loc + (size_t)b * P_NUM * 4))[p];
    float4 ol = ((const float4*)(odm_loc + (size_t)b * P_NUM * 4))[p];
    float cx = __fadd_rn(pr.x, __fmul_rn(__fmul_rn(al.x, 0.1f), pr.z));
    float cy = __fadd_rn(pr.y, __fmul_rn(__fmul_rn(al.y, 0.1f), pr.w));
    float w  = __fmul_rn(pr.z, (float)exp((double)__fmul_rn(al.z, 0.2f)));
    float h  = __fmul_rn(pr.w, (float)exp((double)__fmul_rn(al.w, 0.2f)));
    float mnx = __fsub_rn(cx, __fmul_rn(w, 0.5f));
    float mny = __fsub_rn(cy, __fmul_rn(h, 0.5f));
    float mxx = __fadd_rn(mnx, w);
    float mxy = __fadd_rn(mny, h);
    float dcx = __fmul_rn(__fadd_rn(mxx, mnx), 0.5f);
    float dcy = __fmul_rn(__fadd_rn(mxy, mny), 0.5f);
    float dw  = __fsub_rn(mxx, mnx);
    float dh  = __fsub_rn(mxy, mny);
    float cx2 = __fadd_rn(dcx, __fmul_rn(__fmul_rn(ol.x, 0.1f), dw));
    float cy2 = __fadd_rn(dcy, __fmul_rn(__fmul_rn(ol.y, 0.1f), dh));
    float w2  = __fmul_rn(dw, (float)exp((double)__fmul_rn(ol.z, 0.2f)));
    float h2  = __fmul_rn(dh, (float)exp((double)__fmul_rn(ol.w, 0.2f)));
    float x1 = __fsub_rn(cx2, __fmul_rn(w2, 0.5f));
    float y1 = __fsub_rn(cy2, __fmul_rn(h2, 0.5f));
    float x2 = __fadd_rn(x1, w2);
    float y2 = __fadd_rn(y1, h2);
    box = make_float4(x1, y1, x2, y2);
    area = __fmul_rn(__fsub_rn(x2, x1), __fsub_rn(y2, y1));
}

// =====================  kernel A: select + sort + decode  =====================
__global__ __launch_bounds__(NTHREADS)
void rdet_select(const float* __restrict__ arm_loc,
                 const float* __restrict__ odm_loc,
                 const float* __restrict__ priors,
                 float* __restrict__ ws) {
    __shared__ SMemA sa;
    __shared__ int s_count, s_bstar;
    const int task = blockIdx.x;
    const int tid = threadIdx.x;
    const int b = task / (NCLS - 1);
    float* slab = ws + (size_t)task * P_NUM;

    // ---- Phase 0: load my 32 scores into registers ----
    float s[32];
    {
        const float4* sp = (const float4*)slab;
        #pragma unroll
        for (int v = 0; v < 8; ++v) {
            int q = tid + 512 * v;            // 4080 float4s total
            float4 val = (q < 4080) ? sp[q] : make_float4(0.f, 0.f, 0.f, 0.f);
            s[4 * v + 0] = val.x; s[4 * v + 1] = val.y;
            s[4 * v + 2] = val.z; s[4 * v + 3] = val.w;
        }
    }
    for (int i = tid; i < NBUCKET; i += NTHREADS) sa.hist[i] = 0u;
    if (tid == 0) s_count = 0;
    __syncthreads();

    // ---- Phase 1: histogram ----
    #pragma unroll 4
    for (int k = 0; k < 32; ++k) {
        float sc = s[k];
        if (sc > CONF_THR) {
            int bk = (int)(sc * (float)NBUCKET);
            if (bk > NBUCKET - 1) bk = NBUCKET - 1;
            atomicAdd(&sa.hist[bk], 1u);
        }
    }
    __syncthreads();

    // ---- Phase 2: threshold bucket ----
    {
        int s4 = 0;
        #pragma unroll
        for (int q = 0; q < 4; ++q) s4 += (int)sa.hist[tid * 4 + q];
        sa.csum[tid] = s4;
    }
    __syncthreads();
    if (tid < 64) {
        int g = 0;
        #pragma unroll
        for (int q = 0; q < 8; ++q) g += sa.csum[tid * 8 + q];
        sa.gsum[tid] = g;
    }
    __syncthreads();
    if (tid == 0) {
        int cum = 0, bstar = 0;
        for (int gg = 63; gg >= 0; --gg) {
            int gs = sa.gsum[gg];
            if (cum + gs >= TOPK) {
                for (int t = gg * 8 + 7; t >= gg * 8; --t) {
                    int cs = sa.csum[t];
                    if (cum + cs >= TOPK) {
                        for (int bk = t * 4 + 3; bk >= t * 4; --bk) {
                            cum += (int)sa.hist[bk];
                            if (cum >= TOPK) { bstar = bk; goto found; }
                        }
                    }
                    cum += cs;
                }
            }
            cum += gs;
        }
found:
        s_bstar = bstar;
    }
    __syncthreads();
    const int bstar = s_bstar;

    // ---- Phase 3: gather candidates ----
    #pragma unroll 4
    for (int k = 0; k < 32; ++k) {
        float sc = s[k];
        if (sc > CONF_THR) {
            int bk = (int)(sc * (float)NBUCKET);
            if (bk > NBUCKET - 1) bk = NBUCKET - 1;
            if (bk >= bstar) {
                int p = 4 * (tid + 512 * (k >> 2)) + (k & 3);   // PACKED layout
                int pos = atomicAdd(&s_count, 1);
                if (pos < CAND_CAP) {
                    u64 key = ((u64)__float_as_uint(sc) << 32) | (u32)(~(u32)p);
                    sa.keys[pos] = key;
                }
            }
        }
    }
    __syncthreads();
    int M = s_count; if (M > CAND_CAP) M = CAND_CAP;

    // ---- Phase 4: sort descending ----
    u64 v;
    if (__builtin_expect(M <= 512, 1)) {
        for (int i = M + tid; i < 512; i += NTHREADS) sa.keys[i] = 0ull;
        __syncthreads();
        v = sa.keys[tid];
        #pragma unroll
        for (int k = 2; k <= 512; k <<= 1) {
            for (int j = k >> 1; j > 0; j >>= 1) {
                u64 p;
                if (j >= 64) {
                    sa.keys[tid] = v;
                    __syncthreads();
                    p = sa.keys[tid ^ j];
                    __syncthreads();
                } else {
                    p = __shfl_xor((unsigned long long)v, j, 64);
                }
                const bool desc = ((tid & k) == 0);
                const bool lower = ((tid & j) == 0);
                const bool takeMax = (desc == lower);
                v = (takeMax == (v < p)) ? p : v;
            }
        }
    } else {
        for (int i = M + tid; i < CAND_CAP; i += NTHREADS) sa.keys[i] = 0ull;
        __syncthreads();
        for (int k = 2; k <= CAND_CAP; k <<= 1) {
            for (int j = k >> 1; j > 0; j >>= 1) {
                for (int t = tid; t < CAND_CAP; t += NTHREADS) {
                    int ixj = t ^ j;
                    if (ixj > t) {
                        u64 a = sa.keys[t];
                        u64 bb = sa.keys[ixj];
                        bool desc = ((t & k) == 0);
                        if (desc ? (a < bb) : (a > bb)) {
                            sa.keys[t] = bb;
                            sa.keys[ixj] = a;
                        }
                    }
                }
                __syncthreads();
            }
        }
        v = sa.keys[tid];
    }
    const int N = (M < TOPK) ? M : TOPK;

    // ---- Phase 5: decode + write slab (overlays consumed scores) ----
    float4 box; float area, score;
    if (tid < N) {
        score = __uint_as_float((u32)(v >> 32));
        int p = (int)(~(u32)(v & 0xFFFFFFFFull));
        decode_box(arm_loc, odm_loc, priors, b, p, box, area);
    } else {
        box = make_float4(2.0f, 2.0f, -2.0f, -2.0f);  // inter==0 vs anything; area>0
        area = 16.0f;
        score = 0.0f;
    }
    ((float4*)slab)[tid] = box;
    slab[SLAB_AREA + tid] = area;
    slab[SLAB_SCORE + tid] = score;
    if (tid == 0) ((int*)slab)[SLAB_N] = N;
}

// =====================  kernel B: IoU suppression-mask tiles  =====================
struct BMem {
    float4 sbox[512];     // 8192 B
    float  sarea[512];    // 2048 B
    int    sN;
};

// One column of the folded suppression test.
//   u = fma(-0.45, aj, nai)  (~ -0.45*(ai+aj), 2 roundings)
//   d = fma(1.45, inter, u)  -- sign(d) == sign(inter - 0.45*((aj-inter)+ai))
//   outside the guard zone |d| <= 2.2222e-6*(-u)  (>= 1e-6*(ai+aj) >= 1e-6*denom,
//   vs worst-case fold+div discrepancy ~2.2e-7*denom -> 4x margin).
#define MCOL(bj, aj, jc)  {                                              \
    float xx1 = fmaxf((bj).x, bi.x);                                     \
    float yy1 = fmaxf((bj).y, bi.y);                                     \
    float xx2 = fminf((bj).z, bi.z);                                     \
    float yy2 = fminf((bj).w, bi.w);                                     \
    float iw = fmaxf(__fsub_rn(xx2, xx1), 0.0f);                         \
    float ih = fmaxf(__fsub_rn(yy2, yy1), 0.0f);                         \
    float inter = __fmul_rn(iw, ih);                                     \
    float u = __builtin_fmaf(-NMS_THR, (aj), nai);                       \
    float d = __builtin_fmaf(1.45f, inter, u);                           \
    nearAcc = fminf(nearAcc, __builtin_fmaf(2.2222e-6f, u, fabsf(d)));   \
    bits |= (d > 0.0f) ? (1ull << (jc)) : 0ull;                          \
}

__global__ __launch_bounds__(256)
void rdet_masks(float* __restrict__ ws) {
    __shared__ BMem bm;
    const int task = blockIdx.x / 9;
    const int tg   = blockIdx.x % 9;
    const int tid = threadIdx.x;
    float* slab = ws + (size_t)task * P_NUM;

    // stage sbox + sarea (640 contiguous float4)
    {
        const float4* src = (const float4*)slab;
        for (int q = tid; q < 640; q += 256) {
            float4 vv = src[q];
            if (q < 512) bm.sbox[q] = vv;
            else ((float4*)bm.sarea)[q - 512] = vv;
        }
        if (tid == 0) bm.sN = ((const int*)slab)[SLAB_N];
    }
    __syncthreads();
    const int N = bm.sN;
    const int nblk = (N + 63) >> 6;
    const int wv = tid >> 6;
    const int lane = tid & 63;

    // tile index 0..35 -> (rb, jb) upper-triangular, rb-major.
    // advance guarded by rb==r so it cannot re-trigger after the first failure
    // (round-5 bug).
    const int t = tg * 4 + wv;
    int rb = 0, base = 0;
    #pragma unroll
    for (int r = 0; r < 7; ++r) {
        int cnt = 8 - r;
        if (rb == r && t >= base + cnt) { base += cnt; rb = r + 1; }
    }
    const int jb = rb + (t - base);
    if (jb >= nblk) return;                   // whole wave exits (no barrier below)

    const int i = rb * 64 + lane;
    const float4 bi = bm.sbox[i];
    const float ai = bm.sarea[i];
    const float nai = __fmul_rn(-NMS_THR, ai);
    const int j0 = jb << 6;

    const float4* __restrict__ sb  = &bm.sbox[j0];
    const float4* __restrict__ sa4 = (const float4*)&bm.sarea[j0];

    u64 bits = 0ull;
    float nearAcc = 1.0f;
    // 4-column batches: 4x ds_read_b128 (boxes) + 1x ds_read_b128 (areas)
    // issued together -> single lgkmcnt wait covers 4 columns of VALU.
    #pragma unroll
    for (int q = 0; q < 16; ++q) {
        float4 b0 = sb[4 * q + 0];
        float4 b1 = sb[4 * q + 1];
        float4 b2 = sb[4 * q + 2];
        float4 b3 = sb[4 * q + 3];
        float4 a4 = sa4[q];
        MCOL(b0, a4.x, 4 * q + 0);
        MCOL(b1, a4.y, 4 * q + 1);
        MCOL(b2, a4.z, 4 * q + 2);
        MCOL(b3, a4.w, 4 * q + 3);
    }
    if (__builtin_expect(__any(nearAcc <= 0.0f), 0)) {
        // exact fallback: replicate reference fl(inter/denom) > 0.45f
        bits = 0ull;
        for (int jj = 0; jj < 64; ++jj) {
            const float4 bj = bm.sbox[j0 + jj];
            const float aj = bm.sarea[j0 + jj];
            float xx1 = fmaxf(bj.x, bi.x);
            float yy1 = fmaxf(bj.y, bi.y);
            float xx2 = fminf(bj.z, bi.z);
            float yy2 = fminf(bj.w, bi.w);
            float iw = fmaxf(__fsub_rn(xx2, xx1), 0.0f);
            float ih = fmaxf(__fsub_rn(yy2, yy1), 0.0f);
            float inter = __fmul_rn(iw, ih);
            float denom = __fadd_rn(__fsub_rn(aj, inter), ai);
            bits |= (__fdiv_rn(inter, denom) > NMS_THR) ? (1ull << jj) : 0ull;
        }
    }
    if (jb == rb) bits &= ~((2ull << lane) - 1ull);  // keep j > i only
    u64* tri = (u64*)(slab + SLAB_TRI);
    tri[32 * rb * (17 - rb) + lane * (8 - rb) + (jb - rb)] = bits;
}

// =====================  kernel C: greedy sweep + output  =====================
struct CMem {
    u64    tri[TRI_WORDS];   // FIRST: sweep's masked-out lanes may read up to ~55 words past
    float4 sbox[512];        //        the end; sbox follows so the read stays in-block.
    float  sscore[512];
    int    order[512];
    u64    rowflag[8];
    u64    alive[8];
    int    wordpref[8];
    int    n_emit;
    int    sN;
};

__global__ __launch_bounds__(NTHREADS)
void rdet_nms_out(const float* __restrict__ ws, float* __restrict__ out) {
    __shared__ CMem cm;
    const int task = blockIdx.x;
    const int tid = threadIdx.x;

    if (task >= NTASK) {                      // class-0 slab zeroers
        float* o = out + (size_t)(task - NTASK) * NCLS * TOPK * 5;
        for (int f = tid; f < TOPK * 5; f += NTHREADS) o[f] = 0.0f;
        return;
    }
    const int b = task / (NCLS - 1);
    const int c = task % (NCLS - 1) + 1;
    const float* slab = ws + (size_t)task * P_NUM;

    // stage sbox (f4 0..511), sscore (f4 640..767), tri (f4 772..1923)
    {
        const float4* src = (const float4*)slab;
        for (int q = tid; q < 512; q += NTHREADS) cm.sbox[q] = src[q];
        if (tid < 128) ((float4*)cm.sscore)[tid] = src[640 + tid];
        for (int q = tid; q < 1152; q += NTHREADS) ((float4*)cm.tri)[q] = src[772 + q];
        if (tid == 0) cm.sN = ((const int*)slab)[SLAB_N];
    }
    __syncthreads();
    const int N = cm.sN;
    const int nblk = (N + 63) >> 6;

    // rowflag: one thread per row ORs its row's COMPUTED words only
    {
        int rb = tid >> 6, ln = tid & 63;
        int wstep = 8 - rb;
        int base = 32 * rb * (17 - rb) + ln * wstep;
        int kmax = nblk - rb;                 // computed words for this row block
        u64 o = 0ull;
        for (int k = 0; k < wstep; ++k)
            o |= (k < kmax) ? cm.tri[base + k] : 0ull;
        u64 flag = __ballot(o != 0ull);       // wave == one rb group
        if (ln == 0) cm.rowflag[rb] = flag;
    }
    __syncthreads();

    // greedy sweep, single-wave lane-parallel (lane l owns alive-word l)
    if (tid < 64) {
        const int lane = tid;
        u64 cur = 0ull;
        if (lane < 8) {
            int lo = lane * 64;
            cur = (N >= lo + 64) ? ~0ull
                : (N <= lo)      ? 0ull
                : ((1ull << (N - lo)) - 1ull);
        }
        u64 acc = 0ull;
        for (int w = 0; w < 8; ++w) {
            const int wb = 32 * w * (17 - w);
            const int wstep = 8 - w;
            u64 dm = cm.tri[wb + lane * wstep];       // diag word of row 64w+lane
            u64 f = cm.rowflag[w];
            u64 curw = rl64(cur, w) & ~rl64(acc, w);
            while (f) {
                int bpos = __ffsll((unsigned long long)f) - 1;
                f &= f - 1;
                if ((curw >> bpos) & 1ull) {
                    curw &= ~rl64(dm, bpos);          // in-word, register-resident
                    u64 m = cm.tri[wb + bpos * wstep + (lane - w)];
                    acc |= (lane > w && lane < 8) ? m : 0ull;
                }
            }
            cur = (lane == w) ? curw : cur;
        }
        if (lane < 8) cm.alive[lane] = cur;
    }
    __syncthreads();
    if (tid == 0) {
        int pref = 0;
        #pragma unroll
        for (int w = 0; w < 8; ++w) {
            cm.wordpref[w] = pref;
            pref += __popcll(cm.alive[w]);
        }
        cm.n_emit = pref;
    }
    __syncthreads();
    if (tid < TOPK) {
        int w = tid >> 6, bpos = tid & 63;
        u64 aw = cm.alive[w];
        if ((aw >> bpos) & 1ull) {
            int pos = cm.wordpref[w] + __popcll(aw & ((1ull << bpos) - 1ull));
            cm.order[pos] = tid;
        }
    }
    __syncthreads();

    float* o = out + ((size_t)(b * NCLS + c)) * TOPK * 5;
    const int cnt = cm.n_emit;
    for (int f = tid; f < TOPK * 5; f += NTHREADS) {
        int k = f / 5;
        int r = f - k * 5;
        float val = 0.0f;
        if (k < cnt) {
            int i = cm.order[k];
            float4 bx = cm.sbox[i];
            val = (r == 0) ? cm.sscore[i]
                : (r == 1) ? bx.x
                : (r == 2) ? bx.y
                : (r == 3) ? bx.z
                :            bx.w;
        }
        o[f] = val;
    }
}

// =====================  monolithic fallback (no workspace), round-4 verified  =====================
__global__ __launch_bounds__(NTHREADS)
void refinedet_mono(const float* __restrict__ arm_loc,
                    const float* __restrict__ arm_conf,
                    const float* __restrict__ odm_loc,
                    const float* __restrict__ odm_conf,
                    const float* __restrict__ priors,
                    float* __restrict__ out) {
    __shared__ SMem sm;
    const int task = blockIdx.x;
    const int tid = threadIdx.x;

    if (task >= NTASK) {
        float* o = out + (size_t)(task - NTASK) * NCLS * TOPK * 5;
        for (int f = tid; f < TOPK * 5; f += NTHREADS) o[f] = 0.0f;
        return;
    }

    const int b = task / (NCLS - 1);
    const int c = task % (NCLS - 1) + 1;

    float s[32];
    {
        const float* armc = arm_conf + (size_t)b * P_NUM * 2;
        const float* odmc = odm_conf + (size_t)b * P_NUM * NCLS;
        #pragma unroll 4
        for (int k = 0; k < 32; ++k) {
            int p = tid + 512 * k;
            float sc = 0.0f;
            if (p < P_NUM) {
                float o = armc[p * 2 + 1];
                sc = (o > OBJ_THR) ? odmc[p * NCLS + c] : 0.0f;
            }
            s[k] = sc;
        }
    }
    for (int i = tid; i < NBUCKET; i += NTHREADS) sm.u.a.hist[i] = 0u;
    if (tid == 0) sm.cand_count = 0;
    __syncthreads();

    #pragma unroll 4
    for (int k = 0; k < 32; ++k) {
        float sc = s[k];
        if (sc > CONF_THR) {
            int bk = (int)(sc * (float)NBUCKET);
            if (bk > NBUCKET - 1) bk = NBUCKET - 1;
            atomicAdd(&sm.u.a.hist[bk], 1u);
        }
    }
    __syncthreads();
    {
        int s4 = 0;
        #pragma unroll
        for (int q = 0; q < 4; ++q) s4 += (int)sm.u.a.hist[tid * 4 + q];
        sm.u.a.csum[tid] = s4;
    }
    __syncthreads();
    if (tid < 64) {
        int g = 0;
        #pragma unroll
        for (int q = 0; q < 8; ++q) g += sm.u.a.csum[tid * 8 + q];
        sm.u.a.gsum[tid] = g;
    }
    __syncthreads();
    if (tid == 0) {
        int cum = 0, bstar = 0;
        for (int gg = 63; gg >= 0; --gg) {
            int gs = sm.u.a.gsum[gg];
            if (cum + gs >= TOPK) {
                for (int t = gg * 8 + 7; t >= gg * 8; --t) {
                    int cs = sm.u.a.csum[t];
                    if (cum + cs >= TOPK) {
                        for (int bk = t * 4 + 3; bk >= t * 4; --bk) {
                            cum += (int)sm.u.a.hist[bk];
                            if (cum >= TOPK) { bstar = bk; goto foundm; }
                        }
                    }
                    cum += cs;
                }
            }
            cum += gs;
        }
foundm:
        sm.bstar = bstar;
    }
    __syncthreads();
    const int bstar = sm.bstar;

    #pragma unroll 4
    for (int k = 0; k < 32; ++k) {
        float sc = s[k];
        if (sc > CONF_THR) {
            int bk = (int)(sc * (float)NBUCKET);
            if (bk > NBUCKET - 1) bk = NBUCKET - 1;
            if (bk >= bstar) {
                int p = tid + 512 * k;
                int pos = atomicAdd(&sm.cand_count, 1);
                if (pos < CAND_CAP) {
                    u64 key = ((u64)__float_as_uint(sc) << 32) | (u32)(~(u32)p);
                    sm.u.a.keys[pos] = key;
                }
            }
        }
    }
    __syncthreads();
    int M = sm.cand_count; if (M > CAND_CAP) M = CAND_CAP;

    u64 v;
    if (__builtin_expect(M <= 512, 1)) {
        for (int i = M + tid; i < 512; i += NTHREADS) sm.u.a.keys[i] = 0ull;
        __syncthreads();
        v = sm.u.a.keys[tid];
        #pragma unroll
        for (int k = 2; k <= 512; k <<= 1) {
            for (int j = k >> 1; j > 0; j >>= 1) {
                u64 p;
                if (j >= 64) {
                    sm.u.a.keys[tid] = v;
                    __syncthreads();
                    p = sm.u.a.keys[tid ^ j];
                    __syncthreads();
                } else {
                    p = __shfl_xor((unsigned long long)v, j, 64);
                }
                const bool desc = ((tid & k) == 0);
                const bool lower = ((tid & j) == 0);
                const bool takeMax = (desc == lower);
                v = (takeMax == (v < p)) ? p : v;
            }
        }
    } else {
        for (int i = M + tid; i < CAND_CAP; i += NTHREADS) sm.u.a.keys[i] = 0ull;
        __syncthreads();
        for (int k = 2; k <= CAND_CAP; k <<= 1) {
            for (int j = k >> 1; j > 0; j >>= 1) {
                for (int t = tid; t < CAND_CAP; t += NTHREADS) {
                    int ixj = t ^ j;
                    if (ixj > t) {
                        u64 a = sm.u.a.keys[t];
                        u64 bb = sm.u.a.keys[ixj];
                        bool desc = ((t & k) == 0);
                        if (desc ? (a < bb) : (a > bb)) {
                            sm.u.a.keys[t] = bb;
                            sm.u.a.keys[ixj] = a;
                        }
                    }
                }
                __syncthreads();
            }
        }
        v = sm.u.a.keys[tid];
    }
    const int N = (M < TOPK) ? M : TOPK;

    if (tid < 8) sm.rowflag[tid] = 0ull;
    if (tid < N) {
        float sc = __uint_as_float((u32)(v >> 32));
        int p = (int)(~(u32)(v & 0xFFFFFFFFull));
        float4 box; float area;
        decode_box(arm_loc, odm_loc, priors, b, p, box, area);
        sm.sbox[tid] = box;
        sm.sscore[tid] = sc;
        sm.sarea[tid] = area;
    } else {
        sm.sbox[tid] = make_float4(2.0f, 2.0f, -2.0f, -2.0f);
        sm.sscore[tid] = 0.0f;
        sm.sarea[tid] = 16.0f;
    }
    __syncthreads();

    {
        const int wv = tid >> 6;
        const int lane = tid & 63;
        const int rb = (wv < 4) ? wv : (11 - wv);
        const int i = rb * 64 + lane;
        const float4 bi = sm.sbox[i];
        const float ai = sm.sarea[i];
        const int rowBase = 32 * rb * (17 - rb) + lane * (8 - rb);
        const int nblk = (N + 63) >> 6;
        u64 anyb = 0ull;
        for (int jbk = rb; jbk < nblk; ++jbk) {
            const int j0 = jbk << 6;
            u64 bits = 0ull;
            float nearAcc = 1.0f;
            #pragma unroll 16
            for (int jj = 0; jj < 64; ++jj) {
                const float4 bj = sm.sbox[j0 + jj];
                const float aj = sm.sarea[j0 + jj];
                float xx1 = fmaxf(bj.x, bi.x);
                float yy1 = fmaxf(bj.y, bi.y);
                float xx2 = fminf(bj.z, bi.z);
                float yy2 = fminf(bj.w, bi.w);
                float iw = fmaxf(__fsub_rn(xx2, xx1), 0.0f);
                float ih = fmaxf(__fsub_rn(yy2, yy1), 0.0f);
                float inter = __fmul_rn(iw, ih);
                float denom = __fadd_rn(__fsub_rn(aj, inter), ai);
                float d = __builtin_fmaf(-NMS_THR, denom, inter);
                nearAcc = fminf(nearAcc, __builtin_fmaf(-NEAR_EPS, denom, fabsf(d)));
                bits |= (d > 0.0f) ? (1ull << jj) : 0ull;
            }
            if (__builtin_expect(__any(nearAcc <= 0.0f), 0)) {
                bits = 0ull;
                for (int jj = 0; jj < 64; ++jj) {
                    const float4 bj = sm.sbox[j0 + jj];
                    const float aj = sm.sarea[j0 + jj];
                    float xx1 = fmaxf(bj.x, bi.x);
                    float yy1 = fmaxf(bj.y, bi.y);
                    float xx2 = fminf(bj.z, bi.z);
                    float yy2 = fminf(bj.w, bi.w);
                    float iw = fmaxf(__fsub_rn(xx2, xx1), 0.0f);
                    float ih = fmaxf(__fsub_rn(yy2, yy1), 0.0f);
                    float inter = __fmul_rn(iw, ih);
                    float denom = __fadd_rn(__fsub_rn(aj, inter), ai);
                    bits |= (__fdiv_rn(inter, denom) > NMS_THR) ? (1ull << jj) : 0ull;
                }
            }
            if (jbk == rb) bits &= ~((2ull << lane) - 1ull);
            sm.u.tri[rowBase + (jbk - rb)] = bits;
            anyb |= bits;
        }
        u64 flag = __ballot(anyb != 0ull);
        if (lane == 0) sm.rowflag[rb] = flag;
    }
    __syncthreads();

    if (tid < 64) {
        const int lane = tid;
        u64 cur = 0ull;
        if (lane < 8) {
            int lo = lane * 64;
            cur = (N >= lo + 64) ? ~0ull
                : (N <= lo)      ? 0ull
                : ((1ull << (N - lo)) - 1ull);
        }
        u64 acc = 0ull;
        for (int w = 0; w < 8; ++w) {
            const int wb = 32 * w * (17 - w);
            const int wstep = 8 - w;
            u64 dm = sm.u.tri[wb + lane * wstep];
            u64 f = sm.rowflag[w];
            u64 curw = rl64(cur, w) & ~rl64(acc, w);
            while (f) {
                int bpos = __ffsll((unsigned long long)f) - 1;
                f &= f - 1;
                if ((curw >> bpos) & 1ull) {
                    curw &= ~rl64(dm, bpos);
                    u64 m = sm.u.tri[wb + bpos * wstep + (lane - w)];
                    acc |= (lane > w && lane < 8) ? m : 0ull;
                }
            }
            cur = (lane == w) ? curw : cur;
        }
        if (lane < 8) sm.alive[lane] = cur;
    }
    __syncthreads();
    if (tid == 0) {
        int pref = 0;
        #pragma unroll
        for (int w = 0; w < 8; ++w) {
            sm.wordpref[w] = pref;
            pref += __popcll(sm.alive[w]);
        }
        sm.n_emit = pref;
    }
    __syncthreads();
    if (tid < TOPK) {
        int w = tid >> 6, bpos = tid & 63;
        u64 aw = sm.alive[w];
        if ((aw >> bpos) & 1ull) {
            int pos = sm.wordpref[w] + __popcll(aw & ((1ull << bpos) - 1ull));
            sm.order[pos] = tid;
        }
    }
    __syncthreads();

    float* o = out + ((size_t)(b * NCLS + c)) * TOPK * 5;
    const int cnt = sm.n_emit;
    for (int f = tid; f < TOPK * 5; f += NTHREADS) {
        int k = f / 5;
        int r = f - k * 5;
        float val = 0.0f;
        if (k < cnt) {
            int i = sm.order[k];
            float4 bx = sm.sbox[i];
            val = (r == 0) ? sm.sscore[i]
                : (r == 1) ? bx.x
                : (r == 2) ? bx.y
                : (r == 3) ? bx.z
                :            bx.w;
        }
        o[f] = val;
    }
}

extern "C" void kernel_launch(void* const* d_in, const int* in_sizes, int n_in,
                              void* d_out, int out_size, void* d_ws, size_t ws_size,
                              hipStream_t stream) {
    const float* arm_loc  = (const float*)d_in[0];
    const float* arm_conf = (const float*)d_in[1];
    const float* odm_loc  = (const float*)d_in[2];
    const float* odm_conf = (const float*)d_in[3];
    const float* priors   = (const float*)d_in[4];
    float* out = (float*)d_out;

    const size_t need = (size_t)NTASK * P_NUM * sizeof(float); // 41.8 MB
    if (ws_size >= need) {
        float* wsf = (float*)d_ws;
        mask_transpose<<<B_NUM * 64, 256, 0, stream>>>(arm_conf, odm_conf, wsf);
        rdet_select<<<NTASK, NTHREADS, 0, stream>>>(arm_loc, odm_loc, priors, wsf);
        rdet_masks<<<NTASK * 9, 256, 0, stream>>>(wsf);
        rdet_nms_out<<<NTASK + B_NUM, NTHREADS, 0, stream>>>(wsf, out);
    } else {
        refinedet_mono<<<NTASK + B_NUM, NTHREADS, 0, stream>>>(
            arm_loc, arm_conf, odm_loc, odm_conf, priors, out);
    }
}

// Round 8
// 203.932 us; speedup vs baseline: 1.3136x; 1.0001x over previous
//
#include <hip/hip_runtime.h>
#include <math.h>

#define P_NUM   16320
#define B_NUM   32
#define NCLS    21
#define TOPK    500
#define CONF_THR 0.01f
#define NMS_THR  0.45f
#define OBJ_THR  0.01f
#define NBUCKET 2048
#define CAND_CAP 1024
#define NTHREADS 512
#define CHUNK   256
#define NTASK   (B_NUM * (NCLS - 1))
#define TRI_WORDS 2304       // sum_{b=0..7} 64*(8-b)
#define NEAR_EPS 1e-6f       // guard zone; fma-vs-div disagreement needs ~3e-8 rel

// per-task slab layout inside ws (65,280 B = 16320 floats), overlaying scores:
//   float ofs 0    : sbox  float4[512]   (8192 B)
//   float ofs 2048 : sarea float[512]    (2048 B)
//   float ofs 2560 : sscore float[512]   (2048 B)
//   float ofs 3072 : N (int)
//   float ofs 3088 : tri u64[2304]       (18432 B)  -> ends at float 7696 < 16320
#define SLAB_AREA  2048
#define SLAB_SCORE 2560
#define SLAB_N     3072
#define SLAB_TRI   3088

typedef unsigned long long u64;
typedef unsigned int u32;

struct SMemA {
    u32 hist[NBUCKET];    // 8192 B
    int csum[NTHREADS];   // 2048 B
    int gsum[64];         // 256 B
    u64 keys[CAND_CAP];   // 8192 B  (also cross-wave sort exchange buffer)
};

// monolithic-fallback shared block (kept verbatim from verified round-4 kernel)
struct SMem {
    union {
        SMemA a;            // phases 0-4
        u64 tri[TRI_WORDS]; // triangular mask (phases 6-7)
    } u;
    float4 sbox[512];
    float  sscore[512];
    float  sarea[512];
    int    order[512];
    u64    rowflag[8];
    u64    alive[8];
    int    wordpref[8];
    int    cand_count;
    int    bstar;
    int    n_emit;
};

// ---- mask + transpose odm_conf into per-task contiguous score arrays ----
__global__ __launch_bounds__(256)
void mask_transpose(const float* __restrict__ arm_conf,
                    const float* __restrict__ odm_conf,
                    float* __restrict__ ws) {
    __shared__ float tile[NCLS][CHUNK + 1];
    __shared__ float obj[CHUNK];
    const int blk = blockIdx.x;
    const int b = blk >> 6;
    const int ch = blk & 63;
    const int p0 = ch * CHUNK;
    const int np = min(CHUNK, P_NUM - p0);    // 256, last chunk 192
    const int tid = threadIdx.x;

    const float4* oc4 = (const float4*)(odm_conf + ((size_t)b * P_NUM + p0) * NCLS);
    const float* ac = arm_conf + ((size_t)b * P_NUM + p0) * 2;
    const int count4 = (np * NCLS) / 4;       // 1344 or 1008
    for (int q = tid; q < count4; q += 256) {
        float4 v = oc4[q];                    // coalesced 16B
        int f = 4 * q;
        { int p = f / NCLS;     int cc = f - p * NCLS;     tile[cc][p] = v.x; }
        { int p = (f+1) / NCLS; int cc = (f+1) - p * NCLS; tile[cc][p] = v.y; }
        { int p = (f+2) / NCLS; int cc = (f+2) - p * NCLS; tile[cc][p] = v.z; }
        { int p = (f+3) / NCLS; int cc = (f+3) - p * NCLS; tile[cc][p] = v.w; }
    }
    if (tid < np) obj[tid] = ac[tid * 2 + 1];
    __syncthreads();

    const int nv = np / 4;                    // 64 or 48
    const int total = 20 * nv;
    for (int i = tid; i < total; i += 256) {
        int cc = i / nv;                      // 0..19 -> class cc+1
        int pp = i - cc * nv;
        const float* t = &tile[cc + 1][4 * pp];
        float4 ov = make_float4(
            (obj[4*pp+0] > OBJ_THR) ? t[0] : 0.0f,
            (obj[4*pp+1] > OBJ_THR) ? t[1] : 0.0f,
            (obj[4*pp+2] > OBJ_THR) ? t[2] : 0.0f,
            (obj[4*pp+3] > OBJ_THR) ? t[3] : 0.0f);
        float4* w4 = (float4*)(ws + ((size_t)(b * 20 + cc)) * P_NUM + p0);
        w4[pp] = ov;                          // coalesced 16B store
    }
}

// 64-bit readlane (lane index wave-uniform)
__device__ __forceinline__ u64 rl64(u64 x, int l) {
    u32 lo = (u32)__builtin_amdgcn_readlane((int)(u32)x, l);
    u32 hi = (u32)__builtin_amdgcn_readlane((int)(u32)(x >> 32), l);
    return ((u64)hi << 32) | lo;
}

// ---- decode helper (exact ref FP sequence) ----
__device__ __forceinline__ void decode_box(const float* __restrict__ arm_loc,
                                           const float* __restrict__ odm_loc,
                                           const float* __restrict__ priors,
                                           int b, int p,
                                           float4& box, float& area) {
    float4 pr = ((const float4*)priors)[p];
    float4 al = ((const float4*)(arm_loc + (size_t)b * P_NUM * 4))[p];
    float4 ol = ((const float4*)(odm_loc + (size_t)b * P_NUM * 4))[p];
    float cx = __fadd_rn(pr.x, __fmul_rn(__fmul_rn(al.x, 0.1f), pr.z));
    float cy = __fadd_rn(pr.y, __fmul_rn(__fmul_rn(al.y, 0.1f), pr.w));
    float w  = __fmul_rn(pr.z, (float)exp((double)__fmul_rn(al.z, 0.2f)));
    float h  = __fmul_rn(pr.w, (float)exp((double)__fmul_rn(al.w, 0.2f)));
    float mnx = __fsub_rn(cx, __fmul_rn(w, 0.5f));
    float mny = __fsub_rn(cy, __fmul_rn(h, 0.5f));
    float mxx = __fadd_rn(mnx, w);
    float mxy = __fadd_rn(mny, h);
    float dcx = __fmul_rn(__fadd_rn(mxx, mnx), 0.5f);
    float dcy = __fmul_rn(__fadd_rn(mxy, mny), 0.5f);
    float dw  = __fsub_rn(mxx, mnx);
    float dh  = __fsub_rn(mxy, mny);
    float cx2 = __fadd_rn(dcx, __fmul_rn(__fmul_rn(ol.x, 0.1f), dw));
    float cy2 = __fadd_rn(dcy, __fmul_rn(__fmul_rn(ol.y, 0.1f), dh));
    float w2  = __fmul_rn(dw, (float)exp((double)__fmul_rn(ol.z, 0.2f)));
    float h2  = __fmul_rn(dh, (float)exp((double)__fmul_rn(ol.w, 0.2f)));
    float x1 = __fsub_rn(cx2, __fmul_rn(w2, 0.5f));
    float y1 = __fsub_rn(cy2, __fmul_rn(h2, 0.5f));
    float x2 = __fadd_rn(x1, w2);
    float y2 = __fadd_rn(y1, h2);
    box = make_float4(x1, y1, x2, y2);
    area = __fmul_rn(__fsub_rn(x2, x1), __fsub_rn(y2, y1));
}

// =====================  kernel A: select + sort + decode  =====================
__global__ __launch_bounds__(NTHREADS)
void rdet_select(const float* __restrict__ arm_loc,
                 const float* __restrict__ odm_loc,
                 const float* __restrict__ priors,
                 float* __restrict__ ws) {
    __shared__ SMemA sa;
    __shared__ int s_count, s_bstar;
    const int task = blockIdx.x;
    const int tid = threadIdx.x;
    const int b = task / (NCLS - 1);
    float* slab = ws + (size_t)task * P_NUM;

    // ---- Phase 0: load my 32 scores into registers ----
    float s[32];
    {
        const float4* sp = (const float4*)slab;
        #pragma unroll
        for (int v = 0; v < 8; ++v) {
            int q = tid + 512 * v;            // 4080 float4s total
            float4 val = (q < 4080) ? sp[q] : make_float4(0.f, 0.f, 0.f, 0.f);
            s[4 * v + 0] = val.x; s[4 * v + 1] = val.y;
            s[4 * v + 2] = val.z; s[4 * v + 3] = val.w;
        }
    }
    for (int i = tid; i < NBUCKET; i += NTHREADS) sa.hist[i] = 0u;
    if (tid == 0) s_count = 0;
    __syncthreads();

    // ---- Phase 1: histogram ----
    #pragma unroll 4
    for (int k = 0; k < 32; ++k) {
        float sc = s[k];
        if (sc > CONF_THR) {
            int bk = (int)(sc * (float)NBUCKET);
            if (bk > NBUCKET - 1) bk = NBUCKET - 1;
            atomicAdd(&sa.hist[bk], 1u);
        }
    }
    __syncthreads();

    // ---- Phase 2: threshold bucket (wave-parallel suffix-scan) ----
    {
        int s4 = 0;
        #pragma unroll
        for (int q = 0; q < 4; ++q) s4 += (int)sa.hist[tid * 4 + q];
        sa.csum[tid] = s4;
    }
    __syncthreads();
    if (tid < 64) {
        int g = 0;
        #pragma unroll
        for (int q = 0; q < 8; ++q) g += sa.csum[tid * 8 + q];
        sa.gsum[tid] = g;
    }
    __syncthreads();
    // bstar = max bucket bk with suffix-count B(bk) >= TOPK, else 0.
    // 3-level Kogge-Stone suffix scan + ballot, wave 0 only; equivalent to the
    // old serial top-down walk (verified on concentrated/split/under-TOPK cases).
    if (tid < 64) {
        int sfx = sa.gsum[tid];               // group = 32 buckets
        #pragma unroll
        for (int d = 1; d < 64; d <<= 1) {
            int o = __shfl_down(sfx, d, 64);
            if (tid + d < 64) sfx += o;
        }
        u64 bal = __ballot(sfx >= TOPK);
        int bstar = 0;
        if (bal) {
            int ggs = 63 - __clzll((unsigned long long)bal);  // max group with B >= TOPK
            int tailG = (ggs + 1 < 64) ? __shfl(sfx, ggs + 1, 64) : 0;
            int c = (tid < 8) ? sa.csum[ggs * 8 + tid] : 0;   // quad = 4 buckets
            int s8 = c;
            #pragma unroll
            for (int d = 1; d < 8; d <<= 1) {
                int o = __shfl_down(s8, d, 64);
                if (tid + d < 8) s8 += o;
            }
            s8 += tailG;
            u64 bal2 = __ballot((tid < 8) && (s8 >= TOPK));    // nonzero: s8[0]=B(group start)>=TOPK
            int ts = 63 - __clzll((unsigned long long)bal2);
            int tail3 = (ts + 1 < 8) ? __shfl(s8, ts + 1, 64) : tailG;
            int base = (ggs * 8 + ts) * 4;
            int h = (tid < 4) ? (int)sa.hist[base + tid] : 0;
            int s4v = h;
            #pragma unroll
            for (int d = 1; d < 4; d <<= 1) {
                int o = __shfl_down(s4v, d, 64);
                if (tid + d < 4) s4v += o;
            }
            s4v += tail3;
            u64 bal3 = __ballot((tid < 4) && (s4v >= TOPK));   // nonzero: s4[0]=s8[ts]>=TOPK
            int off = 63 - __clzll((unsigned long long)bal3);
            bstar = base + off;
        }
        if (tid == 0) s_bstar = bstar;
    }
    __syncthreads();
    const int bstar = s_bstar;

    // ---- Phase 3: gather candidates ----
    #pragma unroll 4
    for (int k = 0; k < 32; ++k) {
        float sc = s[k];
        if (sc > CONF_THR) {
            int bk = (int)(sc * (float)NBUCKET);
            if (bk > NBUCKET - 1) bk = NBUCKET - 1;
            if (bk >= bstar) {
                int p = 4 * (tid + 512 * (k >> 2)) + (k & 3);   // PACKED layout
                int pos = atomicAdd(&s_count, 1);
                if (pos < CAND_CAP) {
                    u64 key = ((u64)__float_as_uint(sc) << 32) | (u32)(~(u32)p);
                    sa.keys[pos] = key;
                }
            }
        }
    }
    __syncthreads();
    int M = s_count; if (M > CAND_CAP) M = CAND_CAP;

    // ---- Phase 4: sort descending ----
    u64 v;
    if (__builtin_expect(M <= 512, 1)) {
        for (int i = M + tid; i < 512; i += NTHREADS) sa.keys[i] = 0ull;
        __syncthreads();
        v = sa.keys[tid];
        #pragma unroll
        for (int k = 2; k <= 512; k <<= 1) {
            for (int j = k >> 1; j > 0; j >>= 1) {
                u64 p;
                if (j >= 64) {
                    sa.keys[tid] = v;
                    __syncthreads();
                    p = sa.keys[tid ^ j];
                    __syncthreads();
                } else {
                    p = __shfl_xor((unsigned long long)v, j, 64);
                }
                const bool desc = ((tid & k) == 0);
                const bool lower = ((tid & j) == 0);
                const bool takeMax = (desc == lower);
                v = (takeMax == (v < p)) ? p : v;
            }
        }
    } else {
        for (int i = M + tid; i < CAND_CAP; i += NTHREADS) sa.keys[i] = 0ull;
        __syncthreads();
        for (int k = 2; k <= CAND_CAP; k <<= 1) {
            for (int j = k >> 1; j > 0; j >>= 1) {
                for (int t = tid; t < CAND_CAP; t += NTHREADS) {
                    int ixj = t ^ j;
                    if (ixj > t) {
                        u64 a = sa.keys[t];
                        u64 bb = sa.keys[ixj];
                        bool desc = ((t & k) == 0);
                        if (desc ? (a < bb) : (a > bb)) {
                            sa.keys[t] = bb;
                            sa.keys[ixj] = a;
                        }
                    }
                }
                __syncthreads();
            }
        }
        v = sa.keys[tid];
    }
    const int N = (M < TOPK) ? M : TOPK;

    // ---- Phase 5: decode + write slab (overlays consumed scores) ----
    float4 box; float area, score;
    if (tid < N) {
        score = __uint_as_float((u32)(v >> 32));
        int p = (int)(~(u32)(v & 0xFFFFFFFFull));
        decode_box(arm_loc, odm_loc, priors, b, p, box, area);
    } else {
        box = make_float4(2.0f, 2.0f, -2.0f, -2.0f);  // inter==0 vs anything; area>0
        area = 16.0f;
        score = 0.0f;
    }
    ((float4*)slab)[tid] = box;
    slab[SLAB_AREA + tid] = area;
    slab[SLAB_SCORE + tid] = score;
    if (tid == 0) ((int*)slab)[SLAB_N] = N;
}

// =====================  kernel B: IoU suppression-mask tiles  =====================
struct BMem {
    float4 sbox[512];     // 8192 B
    float  sarea[512];    // 2048 B
    int    sN;
};

__global__ __launch_bounds__(NTHREADS)
void rdet_masks(float* __restrict__ ws) {
    __shared__ BMem bm;
    const int task = blockIdx.x / 5;
    const int tg   = blockIdx.x % 5;
    const int tid = threadIdx.x;
    float* slab = ws + (size_t)task * P_NUM;

    // stage sbox + sarea (640 contiguous float4)
    {
        const float4* src = (const float4*)slab;
        for (int q = tid; q < 640; q += NTHREADS) {
            float4 vv = src[q];
            if (q < 512) bm.sbox[q] = vv;
            else ((float4*)bm.sarea)[q - 512] = vv;
        }
        if (tid == 0) bm.sN = ((const int*)slab)[SLAB_N];
    }
    __syncthreads();
    const int N = bm.sN;
    const int nblk = (N + 63) >> 6;
    const int wv = tid >> 6;
    const int lane = tid & 63;

    // 8 tiles per block, 5 blocks per task; waves with t >= 36 exit after the
    // barrier above (no barrier below).
    const int t = tg * 8 + wv;
    if (t >= 36) return;

    // tile index 0..35 -> (rb, jb) upper-triangular, rb-major.
    // advance guarded by rb==r so it cannot re-trigger after the first failure
    // (round-5 bug).
    int rb = 0, base = 0;
    #pragma unroll
    for (int r = 0; r < 7; ++r) {
        int cnt = 8 - r;
        if (rb == r && t >= base + cnt) { base += cnt; rb = r + 1; }
    }
    const int jb = rb + (t - base);
    if (jb >= nblk) return;                   // whole wave exits

    const int i = rb * 64 + lane;
    const float4 bi = bm.sbox[i];
    const float ai = bm.sarea[i];
    const int j0 = jb << 6;

    u64 bits = 0ull;
    float nearAcc = 1.0f;
    #pragma unroll 16
    for (int jj = 0; jj < 64; ++jj) {
        const float4 bj = bm.sbox[j0 + jj];     // broadcast
        const float aj = bm.sarea[j0 + jj];     // broadcast
        float xx1 = fmaxf(bj.x, bi.x);
        float yy1 = fmaxf(bj.y, bi.y);
        float xx2 = fminf(bj.z, bi.z);
        float yy2 = fminf(bj.w, bi.w);
        float iw = fmaxf(__fsub_rn(xx2, xx1), 0.0f);
        float ih = fmaxf(__fsub_rn(yy2, yy1), 0.0f);
        float inter = __fmul_rn(iw, ih);
        float denom = __fadd_rn(__fsub_rn(aj, inter), ai);   // ref order; > 0 always
        float d = __builtin_fmaf(-NMS_THR, denom, inter);    // sign-exact vs inter-0.45*denom
        nearAcc = fminf(nearAcc, __builtin_fmaf(-NEAR_EPS, denom, fabsf(d)));
        bits |= (d > 0.0f) ? (1ull << jj) : 0ull;
    }
    if (__builtin_expect(__any(nearAcc <= 0.0f), 0)) {
        // exact fallback: replicate reference fl(inter/denom) > 0.45f
        bits = 0ull;
        for (int jj = 0; jj < 64; ++jj) {
            const float4 bj = bm.sbox[j0 + jj];
            const float aj = bm.sarea[j0 + jj];
            float xx1 = fmaxf(bj.x, bi.x);
            float yy1 = fmaxf(bj.y, bi.y);
            float xx2 = fminf(bj.z, bi.z);
            float yy2 = fminf(bj.w, bi.w);
            float iw = fmaxf(__fsub_rn(xx2, xx1), 0.0f);
            float ih = fmaxf(__fsub_rn(yy2, yy1), 0.0f);
            float inter = __fmul_rn(iw, ih);
            float denom = __fadd_rn(__fsub_rn(aj, inter), ai);
            bits |= (__fdiv_rn(inter, denom) > NMS_THR) ? (1ull << jj) : 0ull;
        }
    }
    if (jb == rb) bits &= ~((2ull << lane) - 1ull);  // keep j > i only
    u64* tri = (u64*)(slab + SLAB_TRI);
    tri[32 * rb * (17 - rb) + lane * (8 - rb) + (jb - rb)] = bits;
}

// =====================  kernel C: greedy sweep + output  =====================
struct CMem {
    u64    tri[TRI_WORDS];   // FIRST: sweep's masked-out lanes may read up to ~55 words past
    float4 sbox[512];        //        the end; sbox follows so the read stays in-block.
    float  sscore[512];
    int    order[512];
    u64    rowflag[8];
    u64    alive[8];
    int    wordpref[8];
    int    n_emit;
    int    sN;
};

__global__ __launch_bounds__(NTHREADS)
void rdet_nms_out(const float* __restrict__ ws, float* __restrict__ out) {
    __shared__ CMem cm;
    const int task = blockIdx.x;
    const int tid = threadIdx.x;

    if (task >= NTASK) {                      // class-0 slab zeroers
        float* o = out + (size_t)(task - NTASK) * NCLS * TOPK * 5;
        for (int f = tid; f < TOPK * 5; f += NTHREADS) o[f] = 0.0f;
        return;
    }
    const int b = task / (NCLS - 1);
    const int c = task % (NCLS - 1) + 1;
    const float* slab = ws + (size_t)task * P_NUM;

    // stage sbox (f4 0..511), sscore (f4 640..767), tri (f4 772..1923)
    {
        const float4* src = (const float4*)slab;
        for (int q = tid; q < 512; q += NTHREADS) cm.sbox[q] = src[q];
        if (tid < 128) ((float4*)cm.sscore)[tid] = src[640 + tid];
        for (int q = tid; q < 1152; q += NTHREADS) ((float4*)cm.tri)[q] = src[772 + q];
        if (tid == 0) cm.sN = ((const int*)slab)[SLAB_N];
    }
    __syncthreads();
    const int N = cm.sN;
    const int nblk = (N + 63) >> 6;

    // rowflag: one thread per row ORs its row's COMPUTED words only
    {
        int rb = tid >> 6, ln = tid & 63;
        int wstep = 8 - rb;
        int base = 32 * rb * (17 - rb) + ln * wstep;
        int kmax = nblk - rb;                 // computed words for this row block
        u64 o = 0ull;
        for (int k = 0; k < wstep; ++k)
            o |= (k < kmax) ? cm.tri[base + k] : 0ull;
        u64 flag = __ballot(o != 0ull);       // wave == one rb group
        if (ln == 0) cm.rowflag[rb] = flag;
    }
    __syncthreads();

    // greedy sweep, single-wave lane-parallel (lane l owns alive-word l)
    if (tid < 64) {
        const int lane = tid;
        u64 cur = 0ull;
        if (lane < 8) {
            int lo = lane * 64;
            cur = (N >= lo + 64) ? ~0ull
                : (N <= lo)      ? 0ull
                : ((1ull << (N - lo)) - 1ull);
        }
        u64 acc = 0ull;
        for (int w = 0; w < 8; ++w) {
            const int wb = 32 * w * (17 - w);
            const int wstep = 8 - w;
            u64 dm = cm.tri[wb + lane * wstep];       // diag word of row 64w+lane
            u64 f = cm.rowflag[w];
            u64 curw = rl64(cur, w) & ~rl64(acc, w);
            while (f) {
                int bpos = __ffsll((unsigned long long)f) - 1;
                f &= f - 1;
                if ((curw >> bpos) & 1ull) {
                    curw &= ~rl64(dm, bpos);          // in-word, register-resident
                    u64 m = cm.tri[wb + bpos * wstep + (lane - w)];
                    acc |= (lane > w && lane < 8) ? m : 0ull;
                }
            }
            cur = (lane == w) ? curw : cur;
        }
        if (lane < 8) cm.alive[lane] = cur;
    }
    __syncthreads();
    if (tid == 0) {
        int pref = 0;
        #pragma unroll
        for (int w = 0; w < 8; ++w) {
            cm.wordpref[w] = pref;
            pref += __popcll(cm.alive[w]);
        }
        cm.n_emit = pref;
    }
    __syncthreads();
    if (tid < TOPK) {
        int w = tid >> 6, bpos = tid & 63;
        u64 aw = cm.alive[w];
        if ((aw >> bpos) & 1ull) {
            int pos = cm.wordpref[w] + __popcll(aw & ((1ull << bpos) - 1ull));
            cm.order[pos] = tid;
        }
    }
    __syncthreads();

    float* o = out + ((size_t)(b * NCLS + c)) * TOPK * 5;
    const int cnt = cm.n_emit;
    for (int f = tid; f < TOPK * 5; f += NTHREADS) {
        int k = f / 5;
        int r = f - k * 5;
        float val = 0.0f;
        if (k < cnt) {
            int i = cm.order[k];
            float4 bx = cm.sbox[i];
            val = (r == 0) ? cm.sscore[i]
                : (r == 1) ? bx.x
                : (r == 2) ? bx.y
                : (r == 3) ? bx.z
                :            bx.w;
        }
        o[f] = val;
    }
}

// =====================  monolithic fallback (no workspace), round-4 verified  =====================
__global__ __launch_bounds__(NTHREADS)
void refinedet_mono(const float* __restrict__ arm_loc,
                    const float* __restrict__ arm_conf,
                    const float* __restrict__ odm_loc,
                    const float* __restrict__ odm_conf,
                    const float* __restrict__ priors,
                    float* __restrict__ out) {
    __shared__ SMem sm;
    const int task = blockIdx.x;
    const int tid = threadIdx.x;

    if (task >= NTASK) {
        float* o = out + (size_t)(task - NTASK) * NCLS * TOPK * 5;
        for (int f = tid; f < TOPK * 5; f += NTHREADS) o[f] = 0.0f;
        return;
    }

    const int b = task / (NCLS - 1);
    const int c = task % (NCLS - 1) + 1;

    float s[32];
    {
        const float* armc = arm_conf + (size_t)b * P_NUM * 2;
        const float* odmc = odm_conf + (size_t)b * P_NUM * NCLS;
        #pragma unroll 4
        for (int k = 0; k < 32; ++k) {
            int p = tid + 512 * k;
            float sc = 0.0f;
            if (p < P_NUM) {
                float o = armc[p * 2 + 1];
                sc = (o > OBJ_THR) ? odmc[p * NCLS + c] : 0.0f;
            }
            s[k] = sc;
        }
    }
    for (int i = tid; i < NBUCKET; i += NTHREADS) sm.u.a.hist[i] = 0u;
    if (tid == 0) sm.cand_count = 0;
    __syncthreads();

    #pragma unroll 4
    for (int k = 0; k < 32; ++k) {
        float sc = s[k];
        if (sc > CONF_THR) {
            int bk = (int)(sc * (float)NBUCKET);
            if (bk > NBUCKET - 1) bk = NBUCKET - 1;
            atomicAdd(&sm.u.a.hist[bk], 1u);
        }
    }
    __syncthreads();
    {
        int s4 = 0;
        #pragma unroll
        for (int q = 0; q < 4; ++q) s4 += (int)sm.u.a.hist[tid * 4 + q];
        sm.u.a.csum[tid] = s4;
    }
    __syncthreads();
    if (tid < 64) {
        int g = 0;
        #pragma unroll
        for (int q = 0; q < 8; ++q) g += sm.u.a.csum[tid * 8 + q];
        sm.u.a.gsum[tid] = g;
    }
    __syncthreads();
    if (tid == 0) {
        int cum = 0, bstar = 0;
        for (int gg = 63; gg >= 0; --gg) {
            int gs = sm.u.a.gsum[gg];
            if (cum + gs >= TOPK) {
                for (int t = gg * 8 + 7; t >= gg * 8; --t) {
                    int cs = sm.u.a.csum[t];
                    if (cum + cs >= TOPK) {
                        for (int bk = t * 4 + 3; bk >= t * 4; --bk) {
                            cum += (int)sm.u.a.hist[bk];
                            if (cum >= TOPK) { bstar = bk; goto foundm; }
                        }
                    }
                    cum += cs;
                }
            }
            cum += gs;
        }
foundm:
        sm.bstar = bstar;
    }
    __syncthreads();
    const int bstar = sm.bstar;

    #pragma unroll 4
    for (int k = 0; k < 32; ++k) {
        float sc = s[k];
        if (sc > CONF_THR) {
            int bk = (int)(sc * (float)NBUCKET);
            if (bk > NBUCKET - 1) bk = NBUCKET - 1;
            if (bk >= bstar) {
                int p = tid + 512 * k;
                int pos = atomicAdd(&sm.cand_count, 1);
                if (pos < CAND_CAP) {
                    u64 key = ((u64)__float_as_uint(sc) << 32) | (u32)(~(u32)p);
                    sm.u.a.keys[pos] = key;
                }
            }
        }
    }
    __syncthreads();
    int M = sm.cand_count; if (M > CAND_CAP) M = CAND_CAP;

    u64 v;
    if (__builtin_expect(M <= 512, 1)) {
        for (int i = M + tid; i < 512; i += NTHREADS) sm.u.a.keys[i] = 0ull;
        __syncthreads();
        v = sm.u.a.keys[tid];
        #pragma unroll
        for (int k = 2; k <= 512; k <<= 1) {
            for (int j = k >> 1; j > 0; j >>= 1) {
                u64 p;
                if (j >= 64) {
                    sm.u.a.keys[tid] = v;
                    __syncthreads();
                    p = sm.u.a.keys[tid ^ j];
                    __syncthreads();
                } else {
                    p = __shfl_xor((unsigned long long)v, j, 64);
                }
                const bool desc = ((tid & k) == 0);
                const bool lower = ((tid & j) == 0);
                const bool takeMax = (desc == lower);
                v = (takeMax == (v < p)) ? p : v;
            }
        }
    } else {
        for (int i = M + tid; i < CAND_CAP; i += NTHREADS) sm.u.a.keys[i] = 0ull;
        __syncthreads();
        for (int k = 2; k <= CAND_CAP; k <<= 1) {
            for (int j = k >> 1; j > 0; j >>= 1) {
                for (int t = tid; t < CAND_CAP; t += NTHREADS) {
                    int ixj = t ^ j;
                    if (ixj > t) {
                        u64 a = sm.u.a.keys[t];
                        u64 bb = sm.u.a.keys[ixj];
                        bool desc = ((t & k) == 0);
                        if (desc ? (a < bb) : (a > bb)) {
                            sm.u.a.keys[t] = bb;
                            sm.u.a.keys[ixj] = a;
                        }
                    }
                }
                __syncthreads();
            }
        }
        v = sm.u.a.keys[tid];
    }
    const int N = (M < TOPK) ? M : TOPK;

    if (tid < 8) sm.rowflag[tid] = 0ull;
    if (tid < N) {
        float sc = __uint_as_float((u32)(v >> 32));
        int p = (int)(~(u32)(v & 0xFFFFFFFFull));
        float4 box; float area;
        decode_box(arm_loc, odm_loc, priors, b, p, box, area);
        sm.sbox[tid] = box;
        sm.sscore[tid] = sc;
        sm.sarea[tid] = area;
    } else {
        sm.sbox[tid] = make_float4(2.0f, 2.0f, -2.0f, -2.0f);
        sm.sscore[tid] = 0.0f;
        sm.sarea[tid] = 16.0f;
    }
    __syncthreads();

    {
        const int wv = tid >> 6;
        const int lane = tid & 63;
        const int rb = (wv < 4) ? wv : (11 - wv);
        const int i = rb * 64 + lane;
        const float4 bi = sm.sbox[i];
        const float ai = sm.sarea[i];
        const int rowBase = 32 * rb * (17 - rb) + lane * (8 - rb);
        const int nblk = (N + 63) >> 6;
        u64 anyb = 0ull;
        for (int jbk = rb; jbk < nblk; ++jbk) {
            const int j0 = jbk << 6;
            u64 bits = 0ull;
            float nearAcc = 1.0f;
            #pragma unroll 16
            for (int jj = 0; jj < 64; ++jj) {
                const float4 bj = sm.sbox[j0 + jj];
                const float aj = sm.sarea[j0 + jj];
                float xx1 = fmaxf(bj.x, bi.x);
                float yy1 = fmaxf(bj.y, bi.y);
                float xx2 = fminf(bj.z, bi.z);
                float yy2 = fminf(bj.w, bi.w);
                float iw = fmaxf(__fsub_rn(xx2, xx1), 0.0f);
                float ih = fmaxf(__fsub_rn(yy2, yy1), 0.0f);
                float inter = __fmul_rn(iw, ih);
                float denom = __fadd_rn(__fsub_rn(aj, inter), ai);
                float d = __builtin_fmaf(-NMS_THR, denom, inter);
                nearAcc = fminf(nearAcc, __builtin_fmaf(-NEAR_EPS, denom, fabsf(d)));
                bits |= (d > 0.0f) ? (1ull << jj) : 0ull;
            }
            if (__builtin_expect(__any(nearAcc <= 0.0f), 0)) {
                bits = 0ull;
                for (int jj = 0; jj < 64; ++jj) {
                    const float4 bj = sm.sbox[j0 + jj];
                    const float aj = sm.sarea[j0 + jj];
                    float xx1 = fmaxf(bj.x, bi.x);
                    float yy1 = fmaxf(bj.y, bi.y);
                    float xx2 = fminf(bj.z, bi.z);
                    float yy2 = fminf(bj.w, bi.w);
                    float iw = fmaxf(__fsub_rn(xx2, xx1), 0.0f);
                    float ih = fmaxf(__fsub_rn(yy2, yy1), 0.0f);
                    float inter = __fmul_rn(iw, ih);
                    float denom = __fadd_rn(__fsub_rn(aj, inter), ai);
                    bits |= (__fdiv_rn(inter, denom) > NMS_THR) ? (1ull << jj) : 0ull;
                }
            }
            if (jbk == rb) bits &= ~((2ull << lane) - 1ull);
            sm.u.tri[rowBase + (jbk - rb)] = bits;
            anyb |= bits;
        }
        u64 flag = __ballot(anyb != 0ull);
        if (lane == 0) sm.rowflag[rb] = flag;
    }
    __syncthreads();

    if (tid < 64) {
        const int lane = tid;
        u64 cur = 0ull;
        if (lane < 8) {
            int lo = lane * 64;
            cur = (N >= lo + 64) ? ~0ull
                : (N <= lo)      ? 0ull
                : ((1ull << (N - lo)) - 1ull);
        }
        u64 acc = 0ull;
        for (int w = 0; w < 8; ++w) {
            const int wb = 32 * w * (17 - w);
            const int wstep = 8 - w;
            u64 dm = sm.u.tri[wb + lane * wstep];
            u64 f = sm.rowflag[w];
            u64 curw = rl64(cur, w) & ~rl64(acc, w);
            while (f) {
                int bpos = __ffsll((unsigned long long)f) - 1;
                f &= f - 1;
                if ((curw >> bpos) & 1ull) {
                    curw &= ~rl64(dm, bpos);
                    u64 m = sm.u.tri[wb + bpos * wstep + (lane - w)];
                    acc |= (lane > w && lane < 8) ? m : 0ull;
                }
            }
            cur = (lane == w) ? curw : cur;
        }
        if (lane < 8) sm.alive[lane] = cur;
    }
    __syncthreads();
    if (tid == 0) {
        int pref = 0;
        #pragma unroll
        for (int w = 0; w < 8; ++w) {
            sm.wordpref[w] = pref;
            pref += __popcll(sm.alive[w]);
        }
        sm.n_emit = pref;
    }
    __syncthreads();
    if (tid < TOPK) {
        int w = tid >> 6, bpos = tid & 63;
        u64 aw = sm.alive[w];
        if ((aw >> bpos) & 1ull) {
            int pos = sm.wordpref[w] + __popcll(aw & ((1ull << bpos) - 1ull));
            sm.order[pos] = tid;
        }
    }
    __syncthreads();

    float* o = out + ((size_t)(b * NCLS + c)) * TOPK * 5;
    const int cnt = sm.n_emit;
    for (int f = tid; f < TOPK * 5; f += NTHREADS) {
        int k = f / 5;
        int r = f - k * 5;
        float val = 0.0f;
        if (k < cnt) {
            int i = sm.order[k];
            float4 bx = sm.sbox[i];
            val = (r == 0) ? sm.sscore[i]
                : (r == 1) ? bx.x
                : (r == 2) ? bx.y
                : (r == 3) ? bx.z
                :            bx.w;
        }
        o[f] = val;
    }
}

extern "C" void kernel_launch(void* const* d_in, const int* in_sizes, int n_in,
                              void* d_out, int out_size, void* d_ws, size_t ws_size,
                              hipStream_t stream) {
    const float* arm_loc  = (const float*)d_in[0];
    const float* arm_conf = (const float*)d_in[1];
    const float* odm_loc  = (const float*)d_in[2];
    const float* odm_conf = (const float*)d_in[3];
    const float* priors   = (const float*)d_in[4];
    float* out = (float*)d_out;

    const size_t need = (size_t)NTASK * P_NUM * sizeof(float); // 41.8 MB
    if (ws_size >= need) {
        float* wsf = (float*)d_ws;
        mask_transpose<<<B_NUM * 64, 256, 0, stream>>>(arm_conf, odm_conf, wsf);
        rdet_select<<<NTASK, NTHREADS, 0, stream>>>(arm_loc, odm_loc, priors, wsf);
        rdet_masks<<<NTASK * 5, NTHREADS, 0, stream>>>(wsf);
        rdet_nms_out<<<NTASK + B_NUM, NTHREADS, 0, stream>>>(wsf, out);
    } else {
        refinedet_mono<<<NTASK + B_NUM, NTHREADS, 0, stream>>>(
            arm_loc, arm_conf, odm_loc, odm_conf, priors, out);
    }
}